// Round 8
// baseline (341.554 us; speedup 1.0000x reference)
//
#include <hip/hip_runtime.h>
#include <hip/hip_bf16.h>

#define LTOT 2304
#define ECH  192
#define NCH  16
#define CCH  192  // chunks over L (12 steps each)
#define SCH  12

__device__ __forceinline__ int permS(int k, int l) {
  if (k == 0) return l;
  if (k == 1) return LTOT - 1 - l;
  int m = (k == 2) ? l : (LTOT - 1 - l);
  return (m % 48) * 48 + (m / 48);
}

// fast softplus for x ~ -9: t=e^x tiny -> log1p(t) ~= t(1 - t/2 + t^2/3)
__device__ __forceinline__ float sp_fast(float x) {
  float t = __expf(x);
  return (t <= 0.018f) ? t * fmaf(t, fmaf(t, 0.33333334f, -0.5f), 1.f) : log1pf(t);
}

// ---------------- K1: in_proj GEMM (384x96) -> xi_pre (B,L,E), z (B,L,E) ----------------
// L-tile 32, grid 864. 2pos x 4rows/thread.
__global__ __launch_bounds__(256) void k1_inproj(const float* __restrict__ x,
                                                 const float* __restrict__ W,
                                                 float* __restrict__ xi_pre,
                                                 float* __restrict__ z) {
  const int l0 = blockIdx.x * 32;  // 72
  const int o0 = blockIdx.y * 64;  // 6
  const int b  = blockIdx.z;
  __shared__ __align__(16) float xs[96 * 34];  // [c][pos]
  __shared__ __align__(16) float Wl[96 * 68];  // [c][r]
  const int tid = threadIdx.x;
  for (int idx = tid; idx < 96 * 32; idx += 256) {
    int i = idx & 31, cc = idx >> 5;
    xs[cc * 34 + i] = x[(b * 96 + cc) * LTOT + l0 + i];
  }
  for (int idx = tid; idx < 64 * 96; idx += 256) {
    int r = idx / 96, cc = idx - r * 96;
    Wl[cc * 68 + r] = W[(o0 + r) * 96 + cc];
  }
  __syncthreads();
  const int lane = tid & 63, w = tid >> 6;
  const int jj = lane & 15, rqq = lane >> 4;
  const int rbase = 16 * w + 4 * rqq;
  float acc[2][4];
#pragma unroll
  for (int p = 0; p < 2; ++p)
#pragma unroll
    for (int t = 0; t < 4; ++t) acc[p][t] = 0.f;
#pragma unroll 4
  for (int cc = 0; cc < 96; ++cc) {
    const float4 wv = *(const float4*)&Wl[cc * 68 + rbase];
    const float2 xv = *(const float2*)&xs[cc * 34 + 2 * jj];
    acc[0][0] = fmaf(wv.x, xv.x, acc[0][0]); acc[0][1] = fmaf(wv.y, xv.x, acc[0][1]);
    acc[0][2] = fmaf(wv.z, xv.x, acc[0][2]); acc[0][3] = fmaf(wv.w, xv.x, acc[0][3]);
    acc[1][0] = fmaf(wv.x, xv.y, acc[1][0]); acc[1][1] = fmaf(wv.y, xv.y, acc[1][1]);
    acc[1][2] = fmaf(wv.z, xv.y, acc[1][2]); acc[1][3] = fmaf(wv.w, xv.y, acc[1][3]);
  }
  __syncthreads();
  float* ol = xs;  // [r][pos] pad 33 (64*33 <= 96*34)
#pragma unroll
  for (int t = 0; t < 4; ++t) {
    ol[(rbase + t) * 33 + 2 * jj]     = acc[0][t];
    ol[(rbase + t) * 33 + 2 * jj + 1] = acc[1][t];
  }
  __syncthreads();
  for (int idx = tid; idx < 32 * 64; idx += 256) {
    int r = idx & 63, pos = idx >> 6;
    float v = ol[r * 33 + pos];
    int o = o0 + r, l = l0 + pos;
    if (o < ECH) xi_pre[(b * LTOT + l) * ECH + o] = v;
    else         z[(b * LTOT + l) * ECH + (o - ECH)] = v;
  }
}

// ---------------- K2: depthwise 3x3 conv + SiLU -> xi (B,L,E) ----------------
__global__ __launch_bounds__(256) void k2_dwconv(const float* __restrict__ xi_pre,
                                                 const float* __restrict__ cw,
                                                 const float* __restrict__ cb,
                                                 float* __restrict__ xi) {
  int g = blockIdx.x * 256 + threadIdx.x;
  if (g >= 2 * LTOT * ECH) return;
  int e = g % ECH; int l = (g / ECH) % LTOT; int b = g / (ECH * LTOT);
  int h = l / 48, wq = l % 48;
  float acc = cb[e];
#pragma unroll
  for (int kh = 0; kh < 3; ++kh) {
    int hh = h + kh - 1; if (hh < 0 || hh >= 48) continue;
#pragma unroll
    for (int kw = 0; kw < 3; ++kw) {
      int ww = wq + kw - 1; if (ww < 0 || ww >= 48) continue;
      acc = fmaf(cw[e * 9 + kh * 3 + kw], xi_pre[(b * LTOT + hh * 48 + ww) * ECH + e], acc);
    }
  }
  xi[g] = acc / (1.f + __expf(-acc));
}

// ---------------- K3: x_proj (38x192) -> dl6g (rank-6), bT, cT. Pure GEMM. ----------------
__global__ __launch_bounds__(256) void k3_xproj(const float* __restrict__ xi,
                                                const float* __restrict__ xw,
                                                float* __restrict__ dl6g,
                                                float* __restrict__ bT,
                                                float* __restrict__ cT) {
  const int l0 = blockIdx.x * 32;  // 72
  const int k  = blockIdx.y;       // 4
  const int b  = blockIdx.z;       // 2
  __shared__ __align__(16) float xs[96 * 34];   // [c][j] per c-chunk
  __shared__ __align__(16) float Wl[192 * 40];  // [c][r]
  const int tid = threadIdx.x;
  const float* wsrc = xw + k * 38 * ECH;
  for (int idx = tid; idx < 38 * 192; idx += 256) {
    int r = idx / 192, cc = idx - r * 192;
    Wl[cc * 40 + r] = wsrc[idx];
  }
  const int lane = tid & 63, w = tid >> 6;
  const int jj = lane & 15;
  const int rq = w * 4 + (lane >> 4);   // [0,16), active < 10
  const int rqc = rq < 9 ? rq : 9;
  const int j0 = 2 * jj;
  float a00 = 0.f, a01 = 0.f, a02 = 0.f, a03 = 0.f;
  float a10 = 0.f, a11 = 0.f, a12 = 0.f, a13 = 0.f;
  for (int kc = 0; kc < 2; ++kc) {
    __syncthreads();
    for (int idx = tid; idx < 32 * 96; idx += 256) {
      int j = idx / 96, cc = idx - j * 96;
      int s = permS(k, l0 + j);
      xs[cc * 34 + j] = xi[(b * LTOT + s) * ECH + kc * 96 + cc];
    }
    __syncthreads();
#pragma unroll 4
    for (int cc = 0; cc < 96; ++cc) {
      const float2 xv = *(const float2*)&xs[cc * 34 + j0];
      const float4 wv = *(const float4*)&Wl[(kc * 96 + cc) * 40 + 4 * rqc];
      a00 = fmaf(wv.x, xv.x, a00); a01 = fmaf(wv.y, xv.x, a01);
      a02 = fmaf(wv.z, xv.x, a02); a03 = fmaf(wv.w, xv.x, a03);
      a10 = fmaf(wv.x, xv.y, a10); a11 = fmaf(wv.y, xv.y, a11);
      a12 = fmaf(wv.z, xv.y, a12); a13 = fmaf(wv.w, xv.y, a13);
    }
  }
  const int bk = b * 4 + k;
  if (rq < 10) {
    float av[2][4] = {{a00, a01, a02, a03}, {a10, a11, a12, a13}};
#pragma unroll
    for (int t = 0; t < 4; ++t) {
      int r = 4 * rq + t;
      if (r >= 38) continue;
#pragma unroll
      for (int p = 0; p < 2; ++p) {
        int j = j0 + p;
        float v = av[p][t];
        if (r < 6)       dl6g[((bk * LTOT) + l0 + j) * 6 + r] = v;
        else if (r < 22) bT[((bk * LTOT) + l0 + j) * NCH + (r - 6)] = v;
        else             cT[((bk * LTOT) + l0 + j) * NCH + (r - 22)] = v;
      }
    }
  }
}

// ---------------- K4a: chunk scan pass1 (inline dlt) -> q, Ts. 48-l blocks, 1 barrier. ----------------
__global__ __launch_bounds__(256) void k4a_scan1(const float* __restrict__ dl6g,
                                                 const float* __restrict__ xi,
                                                 const float* __restrict__ bT,
                                                 const float* __restrict__ Alog,
                                                 const float* __restrict__ dtw,
                                                 const float* __restrict__ dtb,
                                                 float* __restrict__ q,
                                                 float* __restrict__ Ts) {
  const int cb = blockIdx.x;  // 48
  const int db = blockIdx.y;  // 3
  const int bk = blockIdx.z;  // 8
  const int b = bk >> 2, k = bk & 3;
  const int l0 = cb * 48;
  __shared__ __align__(16) float2 sdx[48 * 64];
  __shared__ __align__(16) float  sb[48 * NCH];
  const int tid = threadIdx.x;
  const int dd = tid & 63, cg = tid >> 6;
  const int dg = db * 64 + dd;
  float b6 = dtb[k * ECH + dg];
  float w6[6];
  {
    const float2* d2 = (const float2*)(dtw + (k * ECH + dg) * 6);
    float2 u0 = d2[0], u1 = d2[1], u2 = d2[2];
    w6[0] = u0.x; w6[1] = u0.y; w6[2] = u1.x; w6[3] = u1.y; w6[4] = u2.x; w6[5] = u2.y;
  }
  for (int idx = tid; idx < 48 * NCH; idx += 256) sb[idx] = bT[(bk * LTOT + l0) * NCH + idx];
  for (int e = tid; e < 48 * 64; e += 256) {  // dd invariant, s wave-uniform
    int s = e >> 6;
    const float* d6 = dl6g + (bk * LTOT + l0 + s) * 6;
    float xa = b6;
#pragma unroll
    for (int r = 0; r < 6; ++r) xa = fmaf(w6[r], d6[r], xa);
    float dl = sp_fast(xa);
    int sp = permS(k, l0 + s);
    sdx[s * 64 + dd] = make_float2(dl, xi[(b * LTOT + sp) * ECH + dg]);
  }
  float C1[16], h[16];
#pragma unroll
  for (int n = 0; n < 16; ++n) {
    C1[n] = Alog[(k * ECH + dg) * NCH + n];
    h[n] = 0.f;
  }
  __syncthreads();
  float Tsum = 0.f;
  for (int i = 0; i < SCH; ++i) {
    int j = cg * SCH + i;
    float2 dx = sdx[j * 64 + dd];
    float dl = dx.x;
    float u  = dl * dx.y;
    Tsum += dl;
    const float4* bb4 = (const float4*)(sb + j * NCH);
    float4 q0 = bb4[0], q1 = bb4[1], q2 = bb4[2], q3 = bb4[3];
    float bbl[16] = {q0.x, q0.y, q0.z, q0.w, q1.x, q1.y, q1.z, q1.w,
                     q2.x, q2.y, q2.z, q2.w, q3.x, q3.y, q3.z, q3.w};
    if (dl <= 0.018f) {
#pragma unroll
      for (int n = 0; n < 16; ++n) {
        float xn = C1[n] * dl;
        float e = fmaf(xn, fmaf(xn, fmaf(xn, -(1.f / 6.f), 0.5f), -1.f), 1.f);
        h[n] = fmaf(e, h[n], u * bbl[n]);
      }
    } else {
#pragma unroll
      for (int n = 0; n < 16; ++n) {
        float e = __expf(-C1[n] * dl);
        h[n] = fmaf(e, h[n], u * bbl[n]);
      }
    }
  }
  const int c = cb * 4 + cg;
  float4* qp = (float4*)(q + ((bk * CCH + c) * ECH + dg) * NCH);
  qp[0] = make_float4(h[0], h[1], h[2], h[3]);
  qp[1] = make_float4(h[4], h[5], h[6], h[7]);
  qp[2] = make_float4(h[8], h[9], h[10], h[11]);
  qp[3] = make_float4(h[12], h[13], h[14], h[15]);
  Ts[(bk * CCH + c) * ECH + dg] = Tsum;
}

// ---------------- K4b: cross-chunk combine (q -> per-chunk init states, in place) ----------------
__global__ __launch_bounds__(256) void k4b_comb(const float* __restrict__ Alog,
                                                const float* __restrict__ Ts,
                                                float* __restrict__ q) {
  int t = blockIdx.x * 256 + threadIdx.x;
  if (t >= 8 * ECH * NCH) return;
  int n = t & 15, d = (t >> 4) % ECH, bk = t / (NCH * ECH);
  int k = bk & 3;
  float A = Alog[(k * ECH + d) * NCH + n];
  float h = 0.f;
#pragma unroll 4
  for (int c = 0; c < CCH; ++c) {
    int base = ((bk * CCH + c) * ECH + d) * NCH + n;
    float qc = q[base];
    q[base] = h;  // becomes h_init for chunk c
    float xv = A * Ts[(bk * CCH + c) * ECH + d];
    float P = (xv <= 0.05f)
                  ? fmaf(xv, fmaf(xv, fmaf(xv, -(1.f / 6.f), 0.5f), -1.f), 1.f)
                  : __expf(-xv);
    h = fmaf(P, h, qc);
  }
}

// ---------------- K4c: chunk scan pass2 (inline dlt) -> yd[b][k][l][E]. 48-l blocks. ----------------
__global__ __launch_bounds__(256) void k4c_scan2(const float* __restrict__ dl6g,
                                                 const float* __restrict__ xi,
                                                 const float* __restrict__ bT,
                                                 const float* __restrict__ cT,
                                                 const float* __restrict__ Alog,
                                                 const float* __restrict__ dtw,
                                                 const float* __restrict__ dtb,
                                                 const float* __restrict__ hin,
                                                 float* __restrict__ yd) {
  const int cb = blockIdx.x;  // 48
  const int db = blockIdx.y;  // 3
  const int bk = blockIdx.z;  // 8
  const int b = bk >> 2, k = bk & 3;
  const int l0 = cb * 48;
  __shared__ __align__(16) float2 sdx[48 * 64];
  __shared__ __align__(16) float  sb[48 * NCH];
  __shared__ __align__(16) float  sc[48 * NCH];
  const int tid = threadIdx.x;
  const int dd = tid & 63, cg = tid >> 6;
  const int dg = db * 64 + dd;
  float b6 = dtb[k * ECH + dg];
  float w6[6];
  {
    const float2* d2 = (const float2*)(dtw + (k * ECH + dg) * 6);
    float2 u0 = d2[0], u1 = d2[1], u2 = d2[2];
    w6[0] = u0.x; w6[1] = u0.y; w6[2] = u1.x; w6[3] = u1.y; w6[4] = u2.x; w6[5] = u2.y;
  }
  for (int idx = tid; idx < 48 * NCH; idx += 256) {
    sb[idx] = bT[(bk * LTOT + l0) * NCH + idx];
    sc[idx] = cT[(bk * LTOT + l0) * NCH + idx];
  }
  for (int e = tid; e < 48 * 64; e += 256) {
    int s = e >> 6;
    const float* d6 = dl6g + (bk * LTOT + l0 + s) * 6;
    float xa = b6;
#pragma unroll
    for (int r = 0; r < 6; ++r) xa = fmaf(w6[r], d6[r], xa);
    float dl = sp_fast(xa);
    int sp = permS(k, l0 + s);
    sdx[s * 64 + dd] = make_float2(dl, xi[(b * LTOT + sp) * ECH + dg]);
  }
  float C1[16], h[16];
  const int c = cb * 4 + cg;
  const float4* hp = (const float4*)(hin + ((bk * CCH + c) * ECH + dg) * NCH);
  {
    float4 h0 = hp[0], h1 = hp[1], h2 = hp[2], h3 = hp[3];
    h[0]=h0.x; h[1]=h0.y; h[2]=h0.z; h[3]=h0.w;
    h[4]=h1.x; h[5]=h1.y; h[6]=h1.z; h[7]=h1.w;
    h[8]=h2.x; h[9]=h2.y; h[10]=h2.z; h[11]=h2.w;
    h[12]=h3.x; h[13]=h3.y; h[14]=h3.z; h[15]=h3.w;
  }
#pragma unroll
  for (int n = 0; n < 16; ++n) C1[n] = Alog[(k * ECH + dg) * NCH + n];
  float* ydk = yd + (b * 4 + k) * LTOT * ECH;
  __syncthreads();
  for (int i = 0; i < SCH; ++i) {
    int j = cg * SCH + i;
    float2 dx = sdx[j * 64 + dd];
    float dl = dx.x;
    float u  = dl * dx.y;
    const float4* bb4 = (const float4*)(sb + j * NCH);
    float4 q0 = bb4[0], q1 = bb4[1], q2 = bb4[2], q3 = bb4[3];
    float bbl[16] = {q0.x, q0.y, q0.z, q0.w, q1.x, q1.y, q1.z, q1.w,
                     q2.x, q2.y, q2.z, q2.w, q3.x, q3.y, q3.z, q3.w};
    if (dl <= 0.018f) {
#pragma unroll
      for (int n = 0; n < 16; ++n) {
        float xn = C1[n] * dl;
        float e = fmaf(xn, fmaf(xn, fmaf(xn, -(1.f / 6.f), 0.5f), -1.f), 1.f);
        h[n] = fmaf(e, h[n], u * bbl[n]);
      }
    } else {
#pragma unroll
      for (int n = 0; n < 16; ++n) {
        float e = __expf(-C1[n] * dl);
        h[n] = fmaf(e, h[n], u * bbl[n]);
      }
    }
    const float4* cc4 = (const float4*)(sc + j * NCH);
    float4 c0 = cc4[0], c1 = cc4[1], c2 = cc4[2], c3 = cc4[3];
    float ccl[16] = {c0.x, c0.y, c0.z, c0.w, c1.x, c1.y, c1.z, c1.w,
                     c2.x, c2.y, c2.z, c2.w, c3.x, c3.y, c3.z, c3.w};
    float y = 0.f;
#pragma unroll
    for (int n = 0; n < 16; ++n) y = fmaf(h[n], ccl[n], y);
    int sp = permS(k, l0 + j);
    ydk[sp * ECH + dg] = y;
  }
}

// ---------------- K5: LayerNorm over E (+Ds), sum 4 direction buffers, * z ----------------
__global__ __launch_bounds__(256) void k5_ln(const float* __restrict__ yd,
                                             const float* __restrict__ Ds,
                                             const float* __restrict__ lng,
                                             const float* __restrict__ lnb,
                                             float* __restrict__ zu) {
  int p = blockIdx.x * 4 + (threadIdx.x >> 6);
  int lane = threadIdx.x & 63;
  int b = (p >= LTOT) ? 1 : 0;
  int l = p - b * LTOT;
  const float* y0 = yd + (b * 4) * LTOT * ECH + l * ECH;
  float vd[3], sd[3];
#pragma unroll
  for (int t = 0; t < 3; ++t) {
    int d = lane + t * 64;
    vd[t] = ((y0[d] + y0[LTOT * ECH + d]) + y0[2 * LTOT * ECH + d]) + y0[3 * LTOT * ECH + d];
    sd[t] = Ds[d] + Ds[ECH + d] + Ds[2 * ECH + d] + Ds[3 * ECH + d];
  }
  float s1 = vd[0] + vd[1] + vd[2];
  float s2 = sd[0] + sd[1] + sd[2];
#pragma unroll
  for (int off = 32; off > 0; off >>= 1) {
    s1 += __shfl_xor(s1, off, 64);
    s2 += __shfl_xor(s2, off, 64);
  }
  float mean_dot = s1 * (1.f / 192.f);
  float mean_sd  = s2 * (1.f / 192.f);
  float dev[3];
  float ss = 0.f;
#pragma unroll
  for (int t = 0; t < 3; ++t) {
    dev[t] = (vd[t] - mean_dot) + (sd[t] - mean_sd);
    ss = fmaf(dev[t], dev[t], ss);
  }
#pragma unroll
  for (int off = 32; off > 0; off >>= 1) ss += __shfl_xor(ss, off, 64);
  float rstd = 1.f / sqrtf(ss * (1.f / 192.f) + 1e-5f);
#pragma unroll
  for (int t = 0; t < 3; ++t) {
    int d = lane + t * 64;
    float yn = (dev[t] * rstd) * lng[d] + lnb[d];
    zu[p * ECH + d] = yn * zu[p * ECH + d];
  }
}

// ---------------- K6: c1 1x1 GEMM (384x192) + bn1 + relu -> t1 (B,384,L); zeroes se ----------------
// L-tile 32, grid 864. 2pos x 4rows/thread.
__global__ __launch_bounds__(256) void k6_c1(const float* __restrict__ u,
                                             const float* __restrict__ W,
                                             const float* __restrict__ c1b,
                                             const float* __restrict__ g1,
                                             const float* __restrict__ b1,
                                             const float* __restrict__ m1,
                                             const float* __restrict__ v1,
                                             float* __restrict__ t1,
                                             float* __restrict__ se) {
  const int l0 = blockIdx.x * 32;  // 72
  const int o0 = blockIdx.y * 64;  // 6
  const int b  = blockIdx.z;
  const int tid = threadIdx.x;
  if (blockIdx.x == 0 && blockIdx.y == 0 && blockIdx.z == 0 && tid < 192) se[tid] = 0.f;
  __shared__ __align__(16) float xs[96 * 34];  // [c][pos]
  __shared__ __align__(16) float Wl[96 * 68];  // [c][r]
  const int lane = tid & 63, w = tid >> 6;
  const int jj = lane & 15, rqq = lane >> 4;
  const int rbase = 16 * w + 4 * rqq;
  float acc[2][4];
#pragma unroll
  for (int p = 0; p < 2; ++p)
#pragma unroll
    for (int t = 0; t < 4; ++t) acc[p][t] = 0.f;
  for (int kc = 0; kc < 2; ++kc) {
    if (kc) __syncthreads();
    for (int idx = tid; idx < 32 * 96; idx += 256) {
      int cc = idx % 96, i = idx / 96;
      xs[cc * 34 + i] = u[(b * LTOT + l0 + i) * ECH + kc * 96 + cc];
    }
    for (int idx = tid; idx < 64 * 96; idx += 256) {
      int r = idx / 96, cc = idx - r * 96;
      Wl[cc * 68 + r] = W[(o0 + r) * ECH + kc * 96 + cc];
    }
    __syncthreads();
#pragma unroll 4
    for (int cc = 0; cc < 96; ++cc) {
      const float4 wv = *(const float4*)&Wl[cc * 68 + rbase];
      const float2 xv = *(const float2*)&xs[cc * 34 + 2 * jj];
      acc[0][0] = fmaf(wv.x, xv.x, acc[0][0]); acc[0][1] = fmaf(wv.y, xv.x, acc[0][1]);
      acc[0][2] = fmaf(wv.z, xv.x, acc[0][2]); acc[0][3] = fmaf(wv.w, xv.x, acc[0][3]);
      acc[1][0] = fmaf(wv.x, xv.y, acc[1][0]); acc[1][1] = fmaf(wv.y, xv.y, acc[1][1]);
      acc[1][2] = fmaf(wv.z, xv.y, acc[1][2]); acc[1][3] = fmaf(wv.w, xv.y, acc[1][3]);
    }
  }
#pragma unroll
  for (int t = 0; t < 4; ++t) {
    int o = o0 + rbase + t;
    float sc = g1[o] / sqrtf(v1[o] + 1e-5f);
    float bias = (c1b[o] - m1[o]) * sc + b1[o];
#pragma unroll
    for (int p = 0; p < 2; ++p) acc[p][t] = fmaxf(fmaf(acc[p][t], sc, bias), 0.f);
  }
  __syncthreads();
  float* ol = xs;  // [r][pos] pad 33
#pragma unroll
  for (int t = 0; t < 4; ++t) {
    ol[(rbase + t) * 33 + 2 * jj]     = acc[0][t];
    ol[(rbase + t) * 33 + 2 * jj + 1] = acc[1][t];
  }
  __syncthreads();
  for (int idx = tid; idx < 32 * 64; idx += 256) {
    int pos = idx & 31, r = idx >> 5;
    t1[(b * 384 + o0 + r) * LTOT + l0 + pos] = ol[r * 33 + pos];
  }
}

// ---------------- K7: depthwise 3x3 on t1 (B,384,L) + bn2 + relu -> t2 (B,384,L) ----------------
__global__ __launch_bounds__(256) void k7_dw2(const float* __restrict__ t1,
                                              const float* __restrict__ cw,
                                              const float* __restrict__ cb,
                                              const float* __restrict__ g2,
                                              const float* __restrict__ b2,
                                              const float* __restrict__ m2,
                                              const float* __restrict__ v2,
                                              float* __restrict__ t2) {
  int g = blockIdx.x * 256 + threadIdx.x;
  if (g >= 2 * LTOT * 384) return;
  int l = g % LTOT; int o = (g / LTOT) % 384; int b = g / (LTOT * 384);
  int h = l / 48, wq = l % 48;
  const float* src = t1 + (b * 384 + o) * LTOT;
  float acc = cb[o];
#pragma unroll
  for (int kh = 0; kh < 3; ++kh) {
    int hh = h + kh - 1; if (hh < 0 || hh >= 48) continue;
#pragma unroll
    for (int kw = 0; kw < 3; ++kw) {
      int ww = wq + kw - 1; if (ww < 0 || ww >= 48) continue;
      acc = fmaf(cw[o * 9 + kh * 3 + kw], src[hh * 48 + ww], acc);
    }
  }
  float sc = g2[o] / sqrtf(v2[o] + 1e-5f);
  float val = (acc - m2[o]) * sc + b2[o];
  t2[g] = fmaxf(val, 0.f);
}

// ---------------- K8: c3 1x1 GEMM (96x384) on t2 (B,384,L) -> t3 (B,96,L) + SE sums ----------------
__global__ __launch_bounds__(256) void k8_c3(const float* __restrict__ t2,
                                             const float* __restrict__ W,
                                             const float* __restrict__ c3b,
                                             float* __restrict__ t3,
                                             float* __restrict__ se) {
  const int l0 = blockIdx.x * 32;  // 72
  const int r0 = blockIdx.y * 32;  // 3
  const int b  = blockIdx.z;       // 2
  __shared__ __align__(16) float Wl[384 * 34];  // [c][r]
  __shared__ __align__(16) float xs[192 * 34];  // [c][i] per K-half
  const int tid = threadIdx.x;
  const int lane = tid & 63, w = tid >> 6;
  const int jj = lane & 15, rqq = lane >> 4;
  const int rloc = 8 * w + 2 * rqq;
  for (int idx = tid; idx < 32 * 384; idx += 256) {
    int r = idx / 384, cc = idx - r * 384;
    Wl[cc * 34 + r] = W[(r0 + r) * 384 + cc];
  }
  float acc[2][2];
  acc[0][0] = acc[0][1] = acc[1][0] = acc[1][1] = 0.f;
  for (int kc = 0; kc < 2; ++kc) {
    if (kc) __syncthreads();
    for (int idx = tid; idx < 192 * 32; idx += 256) {
      int i = idx & 31, cc = idx >> 5;
      xs[cc * 34 + i] = t2[(b * 384 + kc * 192 + cc) * LTOT + l0 + i];
    }
    __syncthreads();
#pragma unroll 4
    for (int cc = 0; cc < 192; ++cc) {
      const float2 wv = *(const float2*)&Wl[(kc * 192 + cc) * 34 + rloc];
      const float2 xv = *(const float2*)&xs[cc * 34 + 2 * jj];
      acc[0][0] = fmaf(wv.x, xv.x, acc[0][0]); acc[0][1] = fmaf(wv.y, xv.x, acc[0][1]);
      acc[1][0] = fmaf(wv.x, xv.y, acc[1][0]); acc[1][1] = fmaf(wv.y, xv.y, acc[1][1]);
    }
  }
  {
    float b0 = c3b[r0 + rloc], b1v = c3b[r0 + rloc + 1];
    acc[0][0] += b0; acc[1][0] += b0; acc[0][1] += b1v; acc[1][1] += b1v;
  }
#pragma unroll
  for (int t = 0; t < 2; ++t) {
    float v = acc[0][t] + acc[1][t];
    v += __shfl_xor(v, 1); v += __shfl_xor(v, 2);
    v += __shfl_xor(v, 4); v += __shfl_xor(v, 8);
    if (jj == 0) atomicAdd(&se[b * 96 + r0 + rloc + t], v);
  }
  __syncthreads();
  float* ol = xs;  // [r][pos] pad 33
#pragma unroll
  for (int t = 0; t < 2; ++t) {
    ol[(rloc + t) * 33 + 2 * jj]     = acc[0][t];
    ol[(rloc + t) * 33 + 2 * jj + 1] = acc[1][t];
  }
  __syncthreads();
  for (int idx = tid; idx < 32 * 32; idx += 256) {
    int pos = idx & 31, r = idx >> 5;
    t3[(b * 96 + r0 + r) * LTOT + l0 + pos] = ol[r * 33 + pos];
  }
}

// ---------------- K9: SE MLP (per-block, redundant) + out = t3 * (1+sigmoid) ----------------
__global__ __launch_bounds__(256) void k9_out(const float* __restrict__ t3,
                                              const float* __restrict__ se,
                                              const float* __restrict__ w1,
                                              const float* __restrict__ sb1,
                                              const float* __restrict__ w2,
                                              const float* __restrict__ sb2,
                                              float* __restrict__ out) {
  __shared__ float sm[192];
  __shared__ float s1[96];
  __shared__ float smul[192];
  int t = threadIdx.x;
  if (t < 192) sm[t] = se[t] * (1.f / 2304.f);
  __syncthreads();
  if (t < 96) {
    int b = t / 48, i = t % 48;
    float a = sb1[i];
#pragma unroll 4
    for (int m = 0; m < 96; ++m) a = fmaf(w1[i * 96 + m], sm[b * 96 + m], a);
    s1[t] = fmaxf(a, 0.f);
  }
  __syncthreads();
  if (t < 192) {
    int b = t / 96, j = t % 96;
    float a = sb2[j];
#pragma unroll 4
    for (int i = 0; i < 48; ++i) a = fmaf(w2[j * 48 + i], s1[b * 48 + i], a);
    smul[t] = 1.f + 1.f / (1.f + __expf(-a));
  }
  __syncthreads();
  int g = blockIdx.x * 256 + t;
  if (g < 2 * 96 * LTOT) out[g] = t3[g] * smul[g / LTOT];
}

extern "C" void kernel_launch(void* const* d_in, const int* in_sizes, int n_in,
                              void* d_out, int out_size, void* d_ws, size_t ws_size,
                              hipStream_t stream) {
  const float* x     = (const float*)d_in[0];
  const float* inw   = (const float*)d_in[1];
  const float* convw = (const float*)d_in[2];
  const float* convb = (const float*)d_in[3];
  const float* xpw   = (const float*)d_in[4];
  const float* dtw   = (const float*)d_in[5];
  const float* dtb   = (const float*)d_in[6];
  const float* Alog  = (const float*)d_in[7];
  const float* Ds    = (const float*)d_in[8];
  const float* lng   = (const float*)d_in[9];
  const float* lnb   = (const float*)d_in[10];
  const float* c1w   = (const float*)d_in[11];
  const float* c1b   = (const float*)d_in[12];
  const float* bn1g  = (const float*)d_in[13];
  const float* bn1b  = (const float*)d_in[14];
  const float* bn1m  = (const float*)d_in[15];
  const float* bn1v  = (const float*)d_in[16];
  const float* c2w   = (const float*)d_in[17];
  const float* c2b   = (const float*)d_in[18];
  const float* bn2g  = (const float*)d_in[19];
  const float* bn2b  = (const float*)d_in[20];
  const float* bn2m  = (const float*)d_in[21];
  const float* bn2v  = (const float*)d_in[22];
  const float* c3w   = (const float*)d_in[23];
  const float* c3b   = (const float*)d_in[24];
  const float* se1w  = (const float*)d_in[25];
  const float* se1b  = (const float*)d_in[26];
  const float* se2w  = (const float*)d_in[27];
  const float* se2b  = (const float*)d_in[28];

  float* ws = (float*)d_ws;
  float* xi_pre = ws;                    // 884736
  float* z      = ws + 884736;           // 884736 (becomes u after k5)
  float* xi     = ws + 1769472;          // 884736
  float* dl6g   = ws + 2654208;          // 110592
  float* bT     = ws + 2764800;          // 589824
  float* cT     = ws + 3354624;          // 589824
  float* q      = ws + 3944448;          // 9437184 (CCH=192); t3 reuses (dead after k4c)
  float* Ts     = ws + 13381632;         // 294912
  float* se     = ws + 13676544;         // 192
  float* yd     = ws + 13676736;         // 3538944 ; t1/t2 reuse (dead after k5)
  float* t1 = yd;
  float* t2 = yd + 1769472;
  float* t3 = q;

  k1_inproj<<<dim3(72, 6, 2), 256, 0, stream>>>(x, inw, xi_pre, z);
  k2_dwconv<<<3456, 256, 0, stream>>>(xi_pre, convw, convb, xi);
  k3_xproj<<<dim3(72, 4, 2), 256, 0, stream>>>(xi, xpw, dl6g, bT, cT);
  k4a_scan1<<<dim3(48, 3, 8), 256, 0, stream>>>(dl6g, xi, bT, Alog, dtw, dtb, q, Ts);
  k4b_comb<<<96, 256, 0, stream>>>(Alog, Ts, q);
  k4c_scan2<<<dim3(48, 3, 8), 256, 0, stream>>>(dl6g, xi, bT, cT, Alog, dtw, dtb, q, yd);
  k5_ln<<<1152, 256, 0, stream>>>(yd, Ds, lng, lnb, z);
  k6_c1<<<dim3(72, 6, 2), 256, 0, stream>>>(z, c1w, c1b, bn1g, bn1b, bn1m, bn1v, t1, se);
  k7_dw2<<<6912, 256, 0, stream>>>(t1, c2w, c2b, bn2g, bn2b, bn2m, bn2v, t2);
  k8_c3<<<dim3(72, 3, 2), 256, 0, stream>>>(t2, c3w, c3b, t3, se);
  k9_out<<<1728, 256, 0, stream>>>(t3, se, se1w, se1b, se2w, se2b, (float*)d_out);
}

// Round 9
// 300.992 us; speedup vs baseline: 1.1348x; 1.1348x over previous
//
#include <hip/hip_runtime.h>
#include <hip/hip_bf16.h>

#define LTOT 2304
#define ECH  192
#define NCH  16
#define CCH  192  // chunks over L (12 steps each)
#define SCH  12

__device__ __forceinline__ int permS(int k, int l) {
  if (k == 0) return l;
  if (k == 1) return LTOT - 1 - l;
  int m = (k == 2) ? l : (LTOT - 1 - l);
  return (m % 48) * 48 + (m / 48);
}

// fast softplus for x ~ -9: t=e^x tiny -> log1p(t) ~= t(1 - t/2 + t^2/3)
__device__ __forceinline__ float sp_fast(float x) {
  float t = __expf(x);
  return (t <= 0.018f) ? t * fmaf(t, fmaf(t, 0.33333334f, -0.5f), 1.f) : log1pf(t);
}

// ---------------- K1: in_proj GEMM (384x96) -> xi_pre (B,L,E), z (B,L,E) ----------------
__global__ __launch_bounds__(256) void k1_inproj(const float* __restrict__ x,
                                                 const float* __restrict__ W,
                                                 float* __restrict__ xi_pre,
                                                 float* __restrict__ z) {
  const int l0 = blockIdx.x * 32;  // 72
  const int o0 = blockIdx.y * 64;  // 6
  const int b  = blockIdx.z;
  __shared__ __align__(16) float xs[96 * 34];  // [c][pos]
  __shared__ __align__(16) float Wl[96 * 68];  // [c][r]
  const int tid = threadIdx.x;
  for (int idx = tid; idx < 96 * 32; idx += 256) {
    int i = idx & 31, cc = idx >> 5;
    xs[cc * 34 + i] = x[(b * 96 + cc) * LTOT + l0 + i];
  }
  for (int idx = tid; idx < 64 * 96; idx += 256) {
    int r = idx / 96, cc = idx - r * 96;
    Wl[cc * 68 + r] = W[(o0 + r) * 96 + cc];
  }
  __syncthreads();
  const int lane = tid & 63, w = tid >> 6;
  const int jj = lane & 15, rqq = lane >> 4;
  const int rbase = 16 * w + 4 * rqq;
  float acc[2][4];
#pragma unroll
  for (int p = 0; p < 2; ++p)
#pragma unroll
    for (int t = 0; t < 4; ++t) acc[p][t] = 0.f;
#pragma unroll 4
  for (int cc = 0; cc < 96; ++cc) {
    const float4 wv = *(const float4*)&Wl[cc * 68 + rbase];
    const float2 xv = *(const float2*)&xs[cc * 34 + 2 * jj];
    acc[0][0] = fmaf(wv.x, xv.x, acc[0][0]); acc[0][1] = fmaf(wv.y, xv.x, acc[0][1]);
    acc[0][2] = fmaf(wv.z, xv.x, acc[0][2]); acc[0][3] = fmaf(wv.w, xv.x, acc[0][3]);
    acc[1][0] = fmaf(wv.x, xv.y, acc[1][0]); acc[1][1] = fmaf(wv.y, xv.y, acc[1][1]);
    acc[1][2] = fmaf(wv.z, xv.y, acc[1][2]); acc[1][3] = fmaf(wv.w, xv.y, acc[1][3]);
  }
  __syncthreads();
  float* ol = xs;  // [r][pos] pad 33 (64*33 <= 96*34)
#pragma unroll
  for (int t = 0; t < 4; ++t) {
    ol[(rbase + t) * 33 + 2 * jj]     = acc[0][t];
    ol[(rbase + t) * 33 + 2 * jj + 1] = acc[1][t];
  }
  __syncthreads();
  for (int idx = tid; idx < 32 * 64; idx += 256) {
    int r = idx & 63, pos = idx >> 6;
    float v = ol[r * 33 + pos];
    int o = o0 + r, l = l0 + pos;
    if (o < ECH) xi_pre[(b * LTOT + l) * ECH + o] = v;
    else         z[(b * LTOT + l) * ECH + (o - ECH)] = v;
  }
}

// ---------------- K2: depthwise 3x3 conv + SiLU -> xi (B,L,E) ----------------
__global__ __launch_bounds__(256) void k2_dwconv(const float* __restrict__ xi_pre,
                                                 const float* __restrict__ cw,
                                                 const float* __restrict__ cb,
                                                 float* __restrict__ xi) {
  int g = blockIdx.x * 256 + threadIdx.x;
  if (g >= 2 * LTOT * ECH) return;
  int e = g % ECH; int l = (g / ECH) % LTOT; int b = g / (ECH * LTOT);
  int h = l / 48, wq = l % 48;
  float acc = cb[e];
#pragma unroll
  for (int kh = 0; kh < 3; ++kh) {
    int hh = h + kh - 1; if (hh < 0 || hh >= 48) continue;
#pragma unroll
    for (int kw = 0; kw < 3; ++kw) {
      int ww = wq + kw - 1; if (ww < 0 || ww >= 48) continue;
      acc = fmaf(cw[e * 9 + kh * 3 + kw], xi_pre[(b * LTOT + hh * 48 + ww) * ECH + e], acc);
    }
  }
  xi[g] = acc / (1.f + __expf(-acc));
}

// ---------------- K3: x_proj (38x192) -> dl6g (rank-6), bT, cT. Pure GEMM. ----------------
__global__ __launch_bounds__(256) void k3_xproj(const float* __restrict__ xi,
                                                const float* __restrict__ xw,
                                                float* __restrict__ dl6g,
                                                float* __restrict__ bT,
                                                float* __restrict__ cT) {
  const int l0 = blockIdx.x * 32;  // 72
  const int k  = blockIdx.y;       // 4
  const int b  = blockIdx.z;       // 2
  __shared__ __align__(16) float xs[96 * 34];   // [c][j] per c-chunk
  __shared__ __align__(16) float Wl[192 * 40];  // [c][r]
  const int tid = threadIdx.x;
  const float* wsrc = xw + k * 38 * ECH;
  for (int idx = tid; idx < 38 * 192; idx += 256) {
    int r = idx / 192, cc = idx - r * 192;
    Wl[cc * 40 + r] = wsrc[idx];
  }
  const int lane = tid & 63, w = tid >> 6;
  const int jj = lane & 15;
  const int rq = w * 4 + (lane >> 4);   // [0,16), active < 10
  const int rqc = rq < 9 ? rq : 9;
  const int j0 = 2 * jj;
  float a00 = 0.f, a01 = 0.f, a02 = 0.f, a03 = 0.f;
  float a10 = 0.f, a11 = 0.f, a12 = 0.f, a13 = 0.f;
  for (int kc = 0; kc < 2; ++kc) {
    __syncthreads();
    for (int idx = tid; idx < 32 * 96; idx += 256) {
      int j = idx / 96, cc = idx - j * 96;
      int s = permS(k, l0 + j);
      xs[cc * 34 + j] = xi[(b * LTOT + s) * ECH + kc * 96 + cc];
    }
    __syncthreads();
#pragma unroll 4
    for (int cc = 0; cc < 96; ++cc) {
      const float2 xv = *(const float2*)&xs[cc * 34 + j0];
      const float4 wv = *(const float4*)&Wl[(kc * 96 + cc) * 40 + 4 * rqc];
      a00 = fmaf(wv.x, xv.x, a00); a01 = fmaf(wv.y, xv.x, a01);
      a02 = fmaf(wv.z, xv.x, a02); a03 = fmaf(wv.w, xv.x, a03);
      a10 = fmaf(wv.x, xv.y, a10); a11 = fmaf(wv.y, xv.y, a11);
      a12 = fmaf(wv.z, xv.y, a12); a13 = fmaf(wv.w, xv.y, a13);
    }
  }
  const int bk = b * 4 + k;
  if (rq < 10) {
    float av[2][4] = {{a00, a01, a02, a03}, {a10, a11, a12, a13}};
#pragma unroll
    for (int t = 0; t < 4; ++t) {
      int r = 4 * rq + t;
      if (r >= 38) continue;
#pragma unroll
      for (int p = 0; p < 2; ++p) {
        int j = j0 + p;
        float v = av[p][t];
        if (r < 6)       dl6g[((bk * LTOT) + l0 + j) * 6 + r] = v;
        else if (r < 22) bT[((bk * LTOT) + l0 + j) * NCH + (r - 6)] = v;
        else             cT[((bk * LTOT) + l0 + j) * NCH + (r - 22)] = v;
      }
    }
  }
}

// ---------------- K4a: chunk scan pass1 (inline dlt) -> q, Ts. 48-l blocks, 1 barrier. ----------------
__global__ __launch_bounds__(256) void k4a_scan1(const float* __restrict__ dl6g,
                                                 const float* __restrict__ xi,
                                                 const float* __restrict__ bT,
                                                 const float* __restrict__ Alog,
                                                 const float* __restrict__ dtw,
                                                 const float* __restrict__ dtb,
                                                 float* __restrict__ q,
                                                 float* __restrict__ Ts) {
  const int cb = blockIdx.x;  // 48
  const int db = blockIdx.y;  // 3
  const int bk = blockIdx.z;  // 8
  const int b = bk >> 2, k = bk & 3;
  const int l0 = cb * 48;
  __shared__ __align__(16) float2 sdx[48 * 64];
  __shared__ __align__(16) float  sb[48 * NCH];
  const int tid = threadIdx.x;
  const int dd = tid & 63, cg = tid >> 6;
  const int dg = db * 64 + dd;
  float b6 = dtb[k * ECH + dg];
  float w6[6];
  {
    const float2* d2 = (const float2*)(dtw + (k * ECH + dg) * 6);
    float2 u0 = d2[0], u1 = d2[1], u2 = d2[2];
    w6[0] = u0.x; w6[1] = u0.y; w6[2] = u1.x; w6[3] = u1.y; w6[4] = u2.x; w6[5] = u2.y;
  }
  for (int idx = tid; idx < 48 * NCH; idx += 256) sb[idx] = bT[(bk * LTOT + l0) * NCH + idx];
  for (int e = tid; e < 48 * 64; e += 256) {  // dd invariant, s wave-uniform
    int s = e >> 6;
    const float* d6 = dl6g + (bk * LTOT + l0 + s) * 6;
    float xa = b6;
#pragma unroll
    for (int r = 0; r < 6; ++r) xa = fmaf(w6[r], d6[r], xa);
    float dl = sp_fast(xa);
    int sp = permS(k, l0 + s);
    sdx[s * 64 + dd] = make_float2(dl, xi[(b * LTOT + sp) * ECH + dg]);
  }
  float C1[16], h[16];
#pragma unroll
  for (int n = 0; n < 16; ++n) {
    C1[n] = Alog[(k * ECH + dg) * NCH + n];
    h[n] = 0.f;
  }
  __syncthreads();
  float Tsum = 0.f;
  for (int i = 0; i < SCH; ++i) {
    int j = cg * SCH + i;
    float2 dx = sdx[j * 64 + dd];
    float dl = dx.x;
    float u  = dl * dx.y;
    Tsum += dl;
    const float4* bb4 = (const float4*)(sb + j * NCH);
    float4 q0 = bb4[0], q1 = bb4[1], q2 = bb4[2], q3 = bb4[3];
    float bbl[16] = {q0.x, q0.y, q0.z, q0.w, q1.x, q1.y, q1.z, q1.w,
                     q2.x, q2.y, q2.z, q2.w, q3.x, q3.y, q3.z, q3.w};
    if (dl <= 0.018f) {
#pragma unroll
      for (int n = 0; n < 16; ++n) {
        float xn = C1[n] * dl;
        float e = fmaf(xn, fmaf(xn, fmaf(xn, -(1.f / 6.f), 0.5f), -1.f), 1.f);
        h[n] = fmaf(e, h[n], u * bbl[n]);
      }
    } else {
#pragma unroll
      for (int n = 0; n < 16; ++n) {
        float e = __expf(-C1[n] * dl);
        h[n] = fmaf(e, h[n], u * bbl[n]);
      }
    }
  }
  const int c = cb * 4 + cg;
  float4* qp = (float4*)(q + ((bk * CCH + c) * ECH + dg) * NCH);
  qp[0] = make_float4(h[0], h[1], h[2], h[3]);
  qp[1] = make_float4(h[4], h[5], h[6], h[7]);
  qp[2] = make_float4(h[8], h[9], h[10], h[11]);
  qp[3] = make_float4(h[12], h[13], h[14], h[15]);
  Ts[(bk * CCH + c) * ECH + dg] = Tsum;
}

// ---------------- K4b: segmented cross-chunk combine. 16 segs x 12 chunks; grid (192,8). ----------------
__global__ __launch_bounds__(256) void k4b_comb(const float* __restrict__ Alog,
                                                const float* __restrict__ Ts,
                                                float* __restrict__ q) {
  const int d  = blockIdx.x;   // 192
  const int bk = blockIdx.y;   // 8
  const int k  = bk & 3;
  const int tid = threadIdx.x;
  const int n = tid & 15, seg = tid >> 4;  // 16 segments of 12 chunks
  const float A = Alog[(k * ECH + d) * NCH + n];
  const int c0 = seg * 12;
  const float* tb = Ts + (bk * CCH + c0) * ECH + d;
  float* qp = q + ((bk * CCH + c0) * ECH + d) * NCH + n;
  float qv[12], P[12];
#pragma unroll
  for (int i = 0; i < 12; ++i) qv[i] = qp[i * (ECH * NCH)];
#pragma unroll
  for (int i = 0; i < 12; ++i) {
    float xv = A * tb[i * ECH];
    P[i] = (xv <= 0.05f)
               ? fmaf(xv, fmaf(xv, fmaf(xv, -(1.f / 6.f), 0.5f), -1.f), 1.f)
               : __expf(-xv);
  }
  // local scan from zero + composite decay
  float hl = 0.f, Pp = 1.f;
#pragma unroll
  for (int i = 0; i < 12; ++i) { hl = fmaf(P[i], hl, qv[i]); Pp *= P[i]; }
  __shared__ float2 comb[16][17];
  comb[seg][n] = make_float2(Pp, hl);
  __syncthreads();
  float H = 0.f;
  for (int s = 0; s < seg; ++s) {
    float2 cb = comb[s][n];
    H = fmaf(cb.x, H, cb.y);
  }
  // re-emit per-chunk init states
  float h = H;
#pragma unroll
  for (int i = 0; i < 12; ++i) {
    float hp = h;
    h = fmaf(P[i], h, qv[i]);
    qp[i * (ECH * NCH)] = hp;
  }
}

// ---------------- K4c: chunk scan pass2 (inline dlt) -> yd[b][k][l][E]. 48-l blocks. ----------------
__global__ __launch_bounds__(256) void k4c_scan2(const float* __restrict__ dl6g,
                                                 const float* __restrict__ xi,
                                                 const float* __restrict__ bT,
                                                 const float* __restrict__ cT,
                                                 const float* __restrict__ Alog,
                                                 const float* __restrict__ dtw,
                                                 const float* __restrict__ dtb,
                                                 const float* __restrict__ hin,
                                                 float* __restrict__ yd) {
  const int cb = blockIdx.x;  // 48
  const int db = blockIdx.y;  // 3
  const int bk = blockIdx.z;  // 8
  const int b = bk >> 2, k = bk & 3;
  const int l0 = cb * 48;
  __shared__ __align__(16) float2 sdx[48 * 64];
  __shared__ __align__(16) float  sb[48 * NCH];
  __shared__ __align__(16) float  sc[48 * NCH];
  const int tid = threadIdx.x;
  const int dd = tid & 63, cg = tid >> 6;
  const int dg = db * 64 + dd;
  float b6 = dtb[k * ECH + dg];
  float w6[6];
  {
    const float2* d2 = (const float2*)(dtw + (k * ECH + dg) * 6);
    float2 u0 = d2[0], u1 = d2[1], u2 = d2[2];
    w6[0] = u0.x; w6[1] = u0.y; w6[2] = u1.x; w6[3] = u1.y; w6[4] = u2.x; w6[5] = u2.y;
  }
  for (int idx = tid; idx < 48 * NCH; idx += 256) {
    sb[idx] = bT[(bk * LTOT + l0) * NCH + idx];
    sc[idx] = cT[(bk * LTOT + l0) * NCH + idx];
  }
  for (int e = tid; e < 48 * 64; e += 256) {
    int s = e >> 6;
    const float* d6 = dl6g + (bk * LTOT + l0 + s) * 6;
    float xa = b6;
#pragma unroll
    for (int r = 0; r < 6; ++r) xa = fmaf(w6[r], d6[r], xa);
    float dl = sp_fast(xa);
    int sp = permS(k, l0 + s);
    sdx[s * 64 + dd] = make_float2(dl, xi[(b * LTOT + sp) * ECH + dg]);
  }
  float C1[16], h[16];
  const int c = cb * 4 + cg;
  const float4* hp = (const float4*)(hin + ((bk * CCH + c) * ECH + dg) * NCH);
  {
    float4 h0 = hp[0], h1 = hp[1], h2 = hp[2], h3 = hp[3];
    h[0]=h0.x; h[1]=h0.y; h[2]=h0.z; h[3]=h0.w;
    h[4]=h1.x; h[5]=h1.y; h[6]=h1.z; h[7]=h1.w;
    h[8]=h2.x; h[9]=h2.y; h[10]=h2.z; h[11]=h2.w;
    h[12]=h3.x; h[13]=h3.y; h[14]=h3.z; h[15]=h3.w;
  }
#pragma unroll
  for (int n = 0; n < 16; ++n) C1[n] = Alog[(k * ECH + dg) * NCH + n];
  float* ydk = yd + (b * 4 + k) * LTOT * ECH;
  __syncthreads();
  for (int i = 0; i < SCH; ++i) {
    int j = cg * SCH + i;
    float2 dx = sdx[j * 64 + dd];
    float dl = dx.x;
    float u  = dl * dx.y;
    const float4* bb4 = (const float4*)(sb + j * NCH);
    float4 q0 = bb4[0], q1 = bb4[1], q2 = bb4[2], q3 = bb4[3];
    float bbl[16] = {q0.x, q0.y, q0.z, q0.w, q1.x, q1.y, q1.z, q1.w,
                     q2.x, q2.y, q2.z, q2.w, q3.x, q3.y, q3.z, q3.w};
    if (dl <= 0.018f) {
#pragma unroll
      for (int n = 0; n < 16; ++n) {
        float xn = C1[n] * dl;
        float e = fmaf(xn, fmaf(xn, fmaf(xn, -(1.f / 6.f), 0.5f), -1.f), 1.f);
        h[n] = fmaf(e, h[n], u * bbl[n]);
      }
    } else {
#pragma unroll
      for (int n = 0; n < 16; ++n) {
        float e = __expf(-C1[n] * dl);
        h[n] = fmaf(e, h[n], u * bbl[n]);
      }
    }
    const float4* cc4 = (const float4*)(sc + j * NCH);
    float4 c0 = cc4[0], c1 = cc4[1], c2 = cc4[2], c3 = cc4[3];
    float ccl[16] = {c0.x, c0.y, c0.z, c0.w, c1.x, c1.y, c1.z, c1.w,
                     c2.x, c2.y, c2.z, c2.w, c3.x, c3.y, c3.z, c3.w};
    float y = 0.f;
#pragma unroll
    for (int n = 0; n < 16; ++n) y = fmaf(h[n], ccl[n], y);
    int sp = permS(k, l0 + j);
    ydk[sp * ECH + dg] = y;
  }
}

// ---------------- K5: LayerNorm over E (+Ds), sum 4 direction buffers, * z ----------------
__global__ __launch_bounds__(256) void k5_ln(const float* __restrict__ yd,
                                             const float* __restrict__ Ds,
                                             const float* __restrict__ lng,
                                             const float* __restrict__ lnb,
                                             float* __restrict__ zu) {
  int p = blockIdx.x * 4 + (threadIdx.x >> 6);
  int lane = threadIdx.x & 63;
  int b = (p >= LTOT) ? 1 : 0;
  int l = p - b * LTOT;
  const float* y0 = yd + (b * 4) * LTOT * ECH + l * ECH;
  float vd[3], sd[3];
#pragma unroll
  for (int t = 0; t < 3; ++t) {
    int d = lane + t * 64;
    vd[t] = ((y0[d] + y0[LTOT * ECH + d]) + y0[2 * LTOT * ECH + d]) + y0[3 * LTOT * ECH + d];
    sd[t] = Ds[d] + Ds[ECH + d] + Ds[2 * ECH + d] + Ds[3 * ECH + d];
  }
  float s1 = vd[0] + vd[1] + vd[2];
  float s2 = sd[0] + sd[1] + sd[2];
#pragma unroll
  for (int off = 32; off > 0; off >>= 1) {
    s1 += __shfl_xor(s1, off, 64);
    s2 += __shfl_xor(s2, off, 64);
  }
  float mean_dot = s1 * (1.f / 192.f);
  float mean_sd  = s2 * (1.f / 192.f);
  float dev[3];
  float ss = 0.f;
#pragma unroll
  for (int t = 0; t < 3; ++t) {
    dev[t] = (vd[t] - mean_dot) + (sd[t] - mean_sd);
    ss = fmaf(dev[t], dev[t], ss);
  }
#pragma unroll
  for (int off = 32; off > 0; off >>= 1) ss += __shfl_xor(ss, off, 64);
  float rstd = 1.f / sqrtf(ss * (1.f / 192.f) + 1e-5f);
#pragma unroll
  for (int t = 0; t < 3; ++t) {
    int d = lane + t * 64;
    float yn = (dev[t] * rstd) * lng[d] + lnb[d];
    zu[p * ECH + d] = yn * zu[p * ECH + d];
  }
}

// ---------------- K6: c1 1x1 GEMM (384x192) + bn1 + relu -> t1 (B,384,L); zeroes se ----------------
__global__ __launch_bounds__(256) void k6_c1(const float* __restrict__ u,
                                             const float* __restrict__ W,
                                             const float* __restrict__ c1b,
                                             const float* __restrict__ g1,
                                             const float* __restrict__ b1,
                                             const float* __restrict__ m1,
                                             const float* __restrict__ v1,
                                             float* __restrict__ t1,
                                             float* __restrict__ se) {
  const int l0 = blockIdx.x * 32;  // 72
  const int o0 = blockIdx.y * 64;  // 6
  const int b  = blockIdx.z;
  const int tid = threadIdx.x;
  if (blockIdx.x == 0 && blockIdx.y == 0 && blockIdx.z == 0 && tid < 192) se[tid] = 0.f;
  __shared__ __align__(16) float xs[96 * 34];  // [c][pos]
  __shared__ __align__(16) float Wl[96 * 68];  // [c][r]
  const int lane = tid & 63, w = tid >> 6;
  const int jj = lane & 15, rqq = lane >> 4;
  const int rbase = 16 * w + 4 * rqq;
  float acc[2][4];
#pragma unroll
  for (int p = 0; p < 2; ++p)
#pragma unroll
    for (int t = 0; t < 4; ++t) acc[p][t] = 0.f;
  for (int kc = 0; kc < 2; ++kc) {
    if (kc) __syncthreads();
    for (int idx = tid; idx < 32 * 96; idx += 256) {
      int cc = idx % 96, i = idx / 96;
      xs[cc * 34 + i] = u[(b * LTOT + l0 + i) * ECH + kc * 96 + cc];
    }
    for (int idx = tid; idx < 64 * 96; idx += 256) {
      int r = idx / 96, cc = idx - r * 96;
      Wl[cc * 68 + r] = W[(o0 + r) * ECH + kc * 96 + cc];
    }
    __syncthreads();
#pragma unroll 4
    for (int cc = 0; cc < 96; ++cc) {
      const float4 wv = *(const float4*)&Wl[cc * 68 + rbase];
      const float2 xv = *(const float2*)&xs[cc * 34 + 2 * jj];
      acc[0][0] = fmaf(wv.x, xv.x, acc[0][0]); acc[0][1] = fmaf(wv.y, xv.x, acc[0][1]);
      acc[0][2] = fmaf(wv.z, xv.x, acc[0][2]); acc[0][3] = fmaf(wv.w, xv.x, acc[0][3]);
      acc[1][0] = fmaf(wv.x, xv.y, acc[1][0]); acc[1][1] = fmaf(wv.y, xv.y, acc[1][1]);
      acc[1][2] = fmaf(wv.z, xv.y, acc[1][2]); acc[1][3] = fmaf(wv.w, xv.y, acc[1][3]);
    }
  }
#pragma unroll
  for (int t = 0; t < 4; ++t) {
    int o = o0 + rbase + t;
    float sc = g1[o] / sqrtf(v1[o] + 1e-5f);
    float bias = (c1b[o] - m1[o]) * sc + b1[o];
#pragma unroll
    for (int p = 0; p < 2; ++p) acc[p][t] = fmaxf(fmaf(acc[p][t], sc, bias), 0.f);
  }
  __syncthreads();
  float* ol = xs;  // [r][pos] pad 33
#pragma unroll
  for (int t = 0; t < 4; ++t) {
    ol[(rbase + t) * 33 + 2 * jj]     = acc[0][t];
    ol[(rbase + t) * 33 + 2 * jj + 1] = acc[1][t];
  }
  __syncthreads();
  for (int idx = tid; idx < 32 * 64; idx += 256) {
    int pos = idx & 31, r = idx >> 5;
    t1[(b * 384 + o0 + r) * LTOT + l0 + pos] = ol[r * 33 + pos];
  }
}

// ---------------- K7: depthwise 3x3 on t1 (B,384,L) + bn2 + relu -> t2 (B,384,L) ----------------
__global__ __launch_bounds__(256) void k7_dw2(const float* __restrict__ t1,
                                              const float* __restrict__ cw,
                                              const float* __restrict__ cb,
                                              const float* __restrict__ g2,
                                              const float* __restrict__ b2,
                                              const float* __restrict__ m2,
                                              const float* __restrict__ v2,
                                              float* __restrict__ t2) {
  int g = blockIdx.x * 256 + threadIdx.x;
  if (g >= 2 * LTOT * 384) return;
  int l = g % LTOT; int o = (g / LTOT) % 384; int b = g / (LTOT * 384);
  int h = l / 48, wq = l % 48;
  const float* src = t1 + (b * 384 + o) * LTOT;
  float acc = cb[o];
#pragma unroll
  for (int kh = 0; kh < 3; ++kh) {
    int hh = h + kh - 1; if (hh < 0 || hh >= 48) continue;
#pragma unroll
    for (int kw = 0; kw < 3; ++kw) {
      int ww = wq + kw - 1; if (ww < 0 || ww >= 48) continue;
      acc = fmaf(cw[o * 9 + kh * 3 + kw], src[hh * 48 + ww], acc);
    }
  }
  float sc = g2[o] / sqrtf(v2[o] + 1e-5f);
  float val = (acc - m2[o]) * sc + b2[o];
  t2[g] = fmaxf(val, 0.f);
}

// ---------------- K8: c3 1x1 GEMM (96x384) on t2 (B,384,L) -> t3 (B,96,L) + SE sums ----------------
__global__ __launch_bounds__(256) void k8_c3(const float* __restrict__ t2,
                                             const float* __restrict__ W,
                                             const float* __restrict__ c3b,
                                             float* __restrict__ t3,
                                             float* __restrict__ se) {
  const int l0 = blockIdx.x * 32;  // 72
  const int r0 = blockIdx.y * 32;  // 3
  const int b  = blockIdx.z;       // 2
  __shared__ __align__(16) float Wl[384 * 34];  // [c][r]
  __shared__ __align__(16) float xs[192 * 34];  // [c][i] per K-half
  const int tid = threadIdx.x;
  const int lane = tid & 63, w = tid >> 6;
  const int jj = lane & 15, rqq = lane >> 4;
  const int rloc = 8 * w + 2 * rqq;
  for (int idx = tid; idx < 32 * 384; idx += 256) {
    int r = idx / 384, cc = idx - r * 384;
    Wl[cc * 34 + r] = W[(r0 + r) * 384 + cc];
  }
  float acc[2][2];
  acc[0][0] = acc[0][1] = acc[1][0] = acc[1][1] = 0.f;
  for (int kc = 0; kc < 2; ++kc) {
    if (kc) __syncthreads();
    for (int idx = tid; idx < 192 * 32; idx += 256) {
      int i = idx & 31, cc = idx >> 5;
      xs[cc * 34 + i] = t2[(b * 384 + kc * 192 + cc) * LTOT + l0 + i];
    }
    __syncthreads();
#pragma unroll 4
    for (int cc = 0; cc < 192; ++cc) {
      const float2 wv = *(const float2*)&Wl[(kc * 192 + cc) * 34 + rloc];
      const float2 xv = *(const float2*)&xs[cc * 34 + 2 * jj];
      acc[0][0] = fmaf(wv.x, xv.x, acc[0][0]); acc[0][1] = fmaf(wv.y, xv.x, acc[0][1]);
      acc[1][0] = fmaf(wv.x, xv.y, acc[1][0]); acc[1][1] = fmaf(wv.y, xv.y, acc[1][1]);
    }
  }
  {
    float b0 = c3b[r0 + rloc], b1v = c3b[r0 + rloc + 1];
    acc[0][0] += b0; acc[1][0] += b0; acc[0][1] += b1v; acc[1][1] += b1v;
  }
#pragma unroll
  for (int t = 0; t < 2; ++t) {
    float v = acc[0][t] + acc[1][t];
    v += __shfl_xor(v, 1); v += __shfl_xor(v, 2);
    v += __shfl_xor(v, 4); v += __shfl_xor(v, 8);
    if (jj == 0) atomicAdd(&se[b * 96 + r0 + rloc + t], v);
  }
  __syncthreads();
  float* ol = xs;  // [r][pos] pad 33
#pragma unroll
  for (int t = 0; t < 2; ++t) {
    ol[(rloc + t) * 33 + 2 * jj]     = acc[0][t];
    ol[(rloc + t) * 33 + 2 * jj + 1] = acc[1][t];
  }
  __syncthreads();
  for (int idx = tid; idx < 32 * 32; idx += 256) {
    int pos = idx & 31, r = idx >> 5;
    t3[(b * 96 + r0 + r) * LTOT + l0 + pos] = ol[r * 33 + pos];
  }
}

// ---------------- K9: SE MLP (per-block, redundant) + out = t3 * (1+sigmoid) ----------------
__global__ __launch_bounds__(256) void k9_out(const float* __restrict__ t3,
                                              const float* __restrict__ se,
                                              const float* __restrict__ w1,
                                              const float* __restrict__ sb1,
                                              const float* __restrict__ w2,
                                              const float* __restrict__ sb2,
                                              float* __restrict__ out) {
  __shared__ float sm[192];
  __shared__ float s1[96];
  __shared__ float smul[192];
  int t = threadIdx.x;
  if (t < 192) sm[t] = se[t] * (1.f / 2304.f);
  __syncthreads();
  if (t < 96) {
    int b = t / 48, i = t % 48;
    float a = sb1[i];
#pragma unroll 4
    for (int m = 0; m < 96; ++m) a = fmaf(w1[i * 96 + m], sm[b * 96 + m], a);
    s1[t] = fmaxf(a, 0.f);
  }
  __syncthreads();
  if (t < 192) {
    int b = t / 96, j = t % 96;
    float a = sb2[j];
#pragma unroll 4
    for (int i = 0; i < 48; ++i) a = fmaf(w2[j * 48 + i], s1[b * 48 + i], a);
    smul[t] = 1.f + 1.f / (1.f + __expf(-a));
  }
  __syncthreads();
  int g = blockIdx.x * 256 + t;
  if (g < 2 * 96 * LTOT) out[g] = t3[g] * smul[g / LTOT];
}

extern "C" void kernel_launch(void* const* d_in, const int* in_sizes, int n_in,
                              void* d_out, int out_size, void* d_ws, size_t ws_size,
                              hipStream_t stream) {
  const float* x     = (const float*)d_in[0];
  const float* inw   = (const float*)d_in[1];
  const float* convw = (const float*)d_in[2];
  const float* convb = (const float*)d_in[3];
  const float* xpw   = (const float*)d_in[4];
  const float* dtw   = (const float*)d_in[5];
  const float* dtb   = (const float*)d_in[6];
  const float* Alog  = (const float*)d_in[7];
  const float* Ds    = (const float*)d_in[8];
  const float* lng   = (const float*)d_in[9];
  const float* lnb   = (const float*)d_in[10];
  const float* c1w   = (const float*)d_in[11];
  const float* c1b   = (const float*)d_in[12];
  const float* bn1g  = (const float*)d_in[13];
  const float* bn1b  = (const float*)d_in[14];
  const float* bn1m  = (const float*)d_in[15];
  const float* bn1v  = (const float*)d_in[16];
  const float* c2w   = (const float*)d_in[17];
  const float* c2b   = (const float*)d_in[18];
  const float* bn2g  = (const float*)d_in[19];
  const float* bn2b  = (const float*)d_in[20];
  const float* bn2m  = (const float*)d_in[21];
  const float* bn2v  = (const float*)d_in[22];
  const float* c3w   = (const float*)d_in[23];
  const float* c3b   = (const float*)d_in[24];
  const float* se1w  = (const float*)d_in[25];
  const float* se1b  = (const float*)d_in[26];
  const float* se2w  = (const float*)d_in[27];
  const float* se2b  = (const float*)d_in[28];

  float* ws = (float*)d_ws;
  float* xi_pre = ws;                    // 884736
  float* z      = ws + 884736;           // 884736 (becomes u after k5)
  float* xi     = ws + 1769472;          // 884736
  float* dl6g   = ws + 2654208;          // 110592
  float* bT     = ws + 2764800;          // 589824
  float* cT     = ws + 3354624;          // 589824
  float* q      = ws + 3944448;          // 9437184 (CCH=192); t3 reuses (dead after k4c)
  float* Ts     = ws + 13381632;         // 294912
  float* se     = ws + 13676544;         // 192
  float* yd     = ws + 13676736;         // 3538944 ; t1/t2 reuse (dead after k5)
  float* t1 = yd;
  float* t2 = yd + 1769472;
  float* t3 = q;

  k1_inproj<<<dim3(72, 6, 2), 256, 0, stream>>>(x, inw, xi_pre, z);
  k2_dwconv<<<3456, 256, 0, stream>>>(xi_pre, convw, convb, xi);
  k3_xproj<<<dim3(72, 4, 2), 256, 0, stream>>>(xi, xpw, dl6g, bT, cT);
  k4a_scan1<<<dim3(48, 3, 8), 256, 0, stream>>>(dl6g, xi, bT, Alog, dtw, dtb, q, Ts);
  k4b_comb<<<dim3(192, 8), 256, 0, stream>>>(Alog, Ts, q);
  k4c_scan2<<<dim3(48, 3, 8), 256, 0, stream>>>(dl6g, xi, bT, cT, Alog, dtw, dtb, q, yd);
  k5_ln<<<1152, 256, 0, stream>>>(yd, Ds, lng, lnb, z);
  k6_c1<<<dim3(72, 6, 2), 256, 0, stream>>>(z, c1w, c1b, bn1g, bn1b, bn1m, bn1v, t1, se);
  k7_dw2<<<6912, 256, 0, stream>>>(t1, c2w, c2b, bn2g, bn2b, bn2m, bn2v, t2);
  k8_c3<<<dim3(72, 3, 2), 256, 0, stream>>>(t2, c3w, c3b, t3, se);
  k9_out<<<1728, 256, 0, stream>>>(t3, se, se1w, se1b, se2w, se2b, (float*)d_out);
}

// Round 10
// 291.727 us; speedup vs baseline: 1.1708x; 1.0318x over previous
//
#include <hip/hip_runtime.h>
#include <hip/hip_bf16.h>

#define LTOT 2304
#define ECH  192
#define NCH  16
#define CCH  192  // chunks over L (12 steps each)
#define SCH  12

__device__ __forceinline__ int permS(int k, int l) {
  if (k == 0) return l;
  if (k == 1) return LTOT - 1 - l;
  int m = (k == 2) ? l : (LTOT - 1 - l);
  return (m % 48) * 48 + (m / 48);
}

// fast softplus for x ~ -9: t=e^x tiny -> log1p(t) ~= t(1 - t/2 + t^2/3)
__device__ __forceinline__ float sp_fast(float x) {
  float t = __expf(x);
  return (t <= 0.018f) ? t * fmaf(t, fmaf(t, 0.33333334f, -0.5f), 1.f) : log1pf(t);
}

// ---------------- K1: in_proj GEMM (384x96) -> xi_pre (B,L,E), z (B,L,E) ----------------
__global__ __launch_bounds__(256) void k1_inproj(const float* __restrict__ x,
                                                 const float* __restrict__ W,
                                                 float* __restrict__ xi_pre,
                                                 float* __restrict__ z) {
  const int l0 = blockIdx.x * 32;  // 72
  const int o0 = blockIdx.y * 64;  // 6
  const int b  = blockIdx.z;
  __shared__ __align__(16) float xs[96 * 34];  // [c][pos]
  __shared__ __align__(16) float Wl[96 * 68];  // [c][r]
  const int tid = threadIdx.x;
  for (int idx = tid; idx < 96 * 32; idx += 256) {
    int i = idx & 31, cc = idx >> 5;
    xs[cc * 34 + i] = x[(b * 96 + cc) * LTOT + l0 + i];
  }
  // W staging: 4 coalesced row-loads -> one b128 LDS write (kills 8-way write conflicts)
  for (int idx = tid; idx < 96 * 16; idx += 256) {
    int cc = idx % 96, rq = idx / 96;
    float4 v;
    v.x = W[(o0 + 4 * rq + 0) * 96 + cc];
    v.y = W[(o0 + 4 * rq + 1) * 96 + cc];
    v.z = W[(o0 + 4 * rq + 2) * 96 + cc];
    v.w = W[(o0 + 4 * rq + 3) * 96 + cc];
    *(float4*)&Wl[cc * 68 + 4 * rq] = v;
  }
  __syncthreads();
  const int lane = tid & 63, w = tid >> 6;
  const int jj = lane & 15, rqq = lane >> 4;
  const int rbase = 16 * w + 4 * rqq;
  float acc[2][4];
#pragma unroll
  for (int p = 0; p < 2; ++p)
#pragma unroll
    for (int t = 0; t < 4; ++t) acc[p][t] = 0.f;
#pragma unroll 4
  for (int cc = 0; cc < 96; ++cc) {
    const float4 wv = *(const float4*)&Wl[cc * 68 + rbase];
    const float2 xv = *(const float2*)&xs[cc * 34 + 2 * jj];
    acc[0][0] = fmaf(wv.x, xv.x, acc[0][0]); acc[0][1] = fmaf(wv.y, xv.x, acc[0][1]);
    acc[0][2] = fmaf(wv.z, xv.x, acc[0][2]); acc[0][3] = fmaf(wv.w, xv.x, acc[0][3]);
    acc[1][0] = fmaf(wv.x, xv.y, acc[1][0]); acc[1][1] = fmaf(wv.y, xv.y, acc[1][1]);
    acc[1][2] = fmaf(wv.z, xv.y, acc[1][2]); acc[1][3] = fmaf(wv.w, xv.y, acc[1][3]);
  }
  __syncthreads();
  float* ol = xs;  // [r][pos] pad 33 (64*33 <= 96*34)
#pragma unroll
  for (int t = 0; t < 4; ++t) {
    ol[(rbase + t) * 33 + 2 * jj]     = acc[0][t];
    ol[(rbase + t) * 33 + 2 * jj + 1] = acc[1][t];
  }
  __syncthreads();
  for (int idx = tid; idx < 32 * 64; idx += 256) {
    int r = idx & 63, pos = idx >> 6;
    float v = ol[r * 33 + pos];
    int o = o0 + r, l = l0 + pos;
    if (o < ECH) xi_pre[(b * LTOT + l) * ECH + o] = v;
    else         z[(b * LTOT + l) * ECH + (o - ECH)] = v;
  }
}

// ---------------- K2: depthwise 3x3 conv + SiLU -> xi (B,L,E). float4 over e. ----------------
__global__ __launch_bounds__(256) void k2_dwconv(const float4* __restrict__ xi_pre4,
                                                 const float* __restrict__ cw,
                                                 const float* __restrict__ cb,
                                                 float4* __restrict__ xi4) {
  int g = blockIdx.x * 256 + threadIdx.x;
  if (g >= 2 * LTOT * 48) return;
  int e4 = g % 48; int l = (g / 48) % LTOT; int b = g / (48 * LTOT);
  int h = l / 48, wq = l % 48;
  int e0 = 4 * e4;
  float wt[4][9];
#pragma unroll
  for (int j = 0; j < 4; ++j)
#pragma unroll
    for (int t = 0; t < 9; ++t) wt[j][t] = cw[(e0 + j) * 9 + t];
  float4 acc = *(const float4*)&cb[e0];
#pragma unroll
  for (int kh = 0; kh < 3; ++kh) {
    int hh = h + kh - 1; if (hh < 0 || hh >= 48) continue;
#pragma unroll
    for (int kw = 0; kw < 3; ++kw) {
      int ww = wq + kw - 1; if (ww < 0 || ww >= 48) continue;
      float4 v = xi_pre4[(b * LTOT + hh * 48 + ww) * 48 + e4];
      int t = kh * 3 + kw;
      acc.x = fmaf(wt[0][t], v.x, acc.x);
      acc.y = fmaf(wt[1][t], v.y, acc.y);
      acc.z = fmaf(wt[2][t], v.z, acc.z);
      acc.w = fmaf(wt[3][t], v.w, acc.w);
    }
  }
  acc.x = acc.x / (1.f + __expf(-acc.x));
  acc.y = acc.y / (1.f + __expf(-acc.y));
  acc.z = acc.z / (1.f + __expf(-acc.z));
  acc.w = acc.w / (1.f + __expf(-acc.w));
  xi4[g] = acc;
}

// ---------------- K3: x_proj (38x192) -> dl6g (rank-6), bT, cT. Pure GEMM. ----------------
__global__ __launch_bounds__(256) void k3_xproj(const float* __restrict__ xi,
                                                const float* __restrict__ xw,
                                                float* __restrict__ dl6g,
                                                float* __restrict__ bT,
                                                float* __restrict__ cT) {
  const int l0 = blockIdx.x * 32;  // 72
  const int k  = blockIdx.y;       // 4
  const int b  = blockIdx.z;       // 2
  __shared__ __align__(16) float xs[96 * 34];   // [c][j] per c-chunk
  __shared__ __align__(16) float Wl[192 * 44];  // [c][r] pad 44 (8-way not 16-way)
  const int tid = threadIdx.x;
  const float* wsrc = xw + k * 38 * ECH;
  for (int idx = tid; idx < 38 * 192; idx += 256) {
    int r = idx / 192, cc = idx - r * 192;
    Wl[cc * 44 + r] = wsrc[idx];
  }
  const int lane = tid & 63, w = tid >> 6;
  const int jj = lane & 15;
  const int rq = w * 4 + (lane >> 4);   // [0,16), active < 10
  const int rqc = rq < 9 ? rq : 9;
  const int j0 = 2 * jj;
  float a00 = 0.f, a01 = 0.f, a02 = 0.f, a03 = 0.f;
  float a10 = 0.f, a11 = 0.f, a12 = 0.f, a13 = 0.f;
  for (int kc = 0; kc < 2; ++kc) {
    __syncthreads();
    for (int idx = tid; idx < 32 * 96; idx += 256) {
      int j = idx / 96, cc = idx - j * 96;
      int s = permS(k, l0 + j);
      xs[cc * 34 + j] = xi[(b * LTOT + s) * ECH + kc * 96 + cc];
    }
    __syncthreads();
#pragma unroll 4
    for (int cc = 0; cc < 96; ++cc) {
      const float2 xv = *(const float2*)&xs[cc * 34 + j0];
      const float4 wv = *(const float4*)&Wl[(kc * 96 + cc) * 44 + 4 * rqc];
      a00 = fmaf(wv.x, xv.x, a00); a01 = fmaf(wv.y, xv.x, a01);
      a02 = fmaf(wv.z, xv.x, a02); a03 = fmaf(wv.w, xv.x, a03);
      a10 = fmaf(wv.x, xv.y, a10); a11 = fmaf(wv.y, xv.y, a11);
      a12 = fmaf(wv.z, xv.y, a12); a13 = fmaf(wv.w, xv.y, a13);
    }
  }
  const int bk = b * 4 + k;
  if (rq < 10) {
    float av[2][4] = {{a00, a01, a02, a03}, {a10, a11, a12, a13}};
#pragma unroll
    for (int t = 0; t < 4; ++t) {
      int r = 4 * rq + t;
      if (r >= 38) continue;
#pragma unroll
      for (int p = 0; p < 2; ++p) {
        int j = j0 + p;
        float v = av[p][t];
        if (r < 6)       dl6g[((bk * LTOT) + l0 + j) * 6 + r] = v;
        else if (r < 22) bT[((bk * LTOT) + l0 + j) * NCH + (r - 6)] = v;
        else             cT[((bk * LTOT) + l0 + j) * NCH + (r - 22)] = v;
      }
    }
  }
}

// ---------------- K4a: chunk scan pass1 (inline dlt) -> q, Ts. 48-l blocks, 1 barrier. ----------------
__global__ __launch_bounds__(256) void k4a_scan1(const float* __restrict__ dl6g,
                                                 const float* __restrict__ xi,
                                                 const float* __restrict__ bT,
                                                 const float* __restrict__ Alog,
                                                 const float* __restrict__ dtw,
                                                 const float* __restrict__ dtb,
                                                 float* __restrict__ q,
                                                 float* __restrict__ Ts) {
  const int cb = blockIdx.x;  // 48
  const int db = blockIdx.y;  // 3
  const int bk = blockIdx.z;  // 8
  const int b = bk >> 2, k = bk & 3;
  const int l0 = cb * 48;
  __shared__ __align__(16) float2 sdx[48 * 64];
  __shared__ __align__(16) float  sb[48 * NCH];
  const int tid = threadIdx.x;
  const int dd = tid & 63, cg = tid >> 6;
  const int dg = db * 64 + dd;
  float b6 = dtb[k * ECH + dg];
  float w6[6];
  {
    const float2* d2 = (const float2*)(dtw + (k * ECH + dg) * 6);
    float2 u0 = d2[0], u1 = d2[1], u2 = d2[2];
    w6[0] = u0.x; w6[1] = u0.y; w6[2] = u1.x; w6[3] = u1.y; w6[4] = u2.x; w6[5] = u2.y;
  }
  for (int idx = tid; idx < 48 * NCH; idx += 256) sb[idx] = bT[(bk * LTOT + l0) * NCH + idx];
  for (int e = tid; e < 48 * 64; e += 256) {  // dd invariant, s wave-uniform
    int s = e >> 6;
    const float* d6 = dl6g + (bk * LTOT + l0 + s) * 6;
    float xa = b6;
#pragma unroll
    for (int r = 0; r < 6; ++r) xa = fmaf(w6[r], d6[r], xa);
    float dl = sp_fast(xa);
    int sp = permS(k, l0 + s);
    sdx[s * 64 + dd] = make_float2(dl, dl * xi[(b * LTOT + sp) * ECH + dg]);
  }
  float C1[16], h[16];
#pragma unroll
  for (int n = 0; n < 16; ++n) {
    C1[n] = Alog[(k * ECH + dg) * NCH + n];
    h[n] = 0.f;
  }
  __syncthreads();
  float Tsum = 0.f;
  for (int i = 0; i < SCH; ++i) {
    int j = cg * SCH + i;
    float2 dx = sdx[j * 64 + dd];
    float dl = dx.x;
    float u  = dx.y;
    Tsum += dl;
    const float4* bb4 = (const float4*)(sb + j * NCH);
    float4 q0 = bb4[0], q1 = bb4[1], q2 = bb4[2], q3 = bb4[3];
    float bbl[16] = {q0.x, q0.y, q0.z, q0.w, q1.x, q1.y, q1.z, q1.w,
                     q2.x, q2.y, q2.z, q2.w, q3.x, q3.y, q3.z, q3.w};
    if (dl <= 0.018f) {
#pragma unroll
      for (int n = 0; n < 16; ++n) {
        float xn = C1[n] * dl;
        float e = fmaf(xn, fmaf(xn, fmaf(xn, -(1.f / 6.f), 0.5f), -1.f), 1.f);
        h[n] = fmaf(e, h[n], u * bbl[n]);
      }
    } else {
#pragma unroll
      for (int n = 0; n < 16; ++n) {
        float e = __expf(-C1[n] * dl);
        h[n] = fmaf(e, h[n], u * bbl[n]);
      }
    }
  }
  const int c = cb * 4 + cg;
  float4* qp = (float4*)(q + ((bk * CCH + c) * ECH + dg) * NCH);
  qp[0] = make_float4(h[0], h[1], h[2], h[3]);
  qp[1] = make_float4(h[4], h[5], h[6], h[7]);
  qp[2] = make_float4(h[8], h[9], h[10], h[11]);
  qp[3] = make_float4(h[12], h[13], h[14], h[15]);
  Ts[(bk * CCH + c) * ECH + dg] = Tsum;
}

// ---------------- K4b: segmented cross-chunk combine. 16 segs x 12 chunks; grid (192,8). ----------------
__global__ __launch_bounds__(256) void k4b_comb(const float* __restrict__ Alog,
                                                const float* __restrict__ Ts,
                                                float* __restrict__ q) {
  const int d  = blockIdx.x;   // 192
  const int bk = blockIdx.y;   // 8
  const int k  = bk & 3;
  const int tid = threadIdx.x;
  const int n = tid & 15, seg = tid >> 4;  // 16 segments of 12 chunks
  const float A = Alog[(k * ECH + d) * NCH + n];
  const int c0 = seg * 12;
  const float* tb = Ts + (bk * CCH + c0) * ECH + d;
  float* qp = q + ((bk * CCH + c0) * ECH + d) * NCH + n;
  float qv[12], P[12];
#pragma unroll
  for (int i = 0; i < 12; ++i) qv[i] = qp[i * (ECH * NCH)];
#pragma unroll
  for (int i = 0; i < 12; ++i) {
    float xv = A * tb[i * ECH];
    P[i] = (xv <= 0.05f)
               ? fmaf(xv, fmaf(xv, fmaf(xv, -(1.f / 6.f), 0.5f), -1.f), 1.f)
               : __expf(-xv);
  }
  float hl = 0.f, Pp = 1.f;
#pragma unroll
  for (int i = 0; i < 12; ++i) { hl = fmaf(P[i], hl, qv[i]); Pp *= P[i]; }
  __shared__ float2 comb[16][17];
  comb[seg][n] = make_float2(Pp, hl);
  __syncthreads();
  float H = 0.f;
  for (int s = 0; s < seg; ++s) {
    float2 cb = comb[s][n];
    H = fmaf(cb.x, H, cb.y);
  }
  float h = H;
#pragma unroll
  for (int i = 0; i < 12; ++i) {
    float hp = h;
    h = fmaf(P[i], h, qv[i]);
    qp[i * (ECH * NCH)] = hp;
  }
}

// ---------------- K4c: chunk scan pass2 (inline dlt) -> atomicAdd into ys (B,L,E). ----------------
__global__ __launch_bounds__(256) void k4c_scan2(const float* __restrict__ dl6g,
                                                 const float* __restrict__ xi,
                                                 const float* __restrict__ bT,
                                                 const float* __restrict__ cT,
                                                 const float* __restrict__ Alog,
                                                 const float* __restrict__ dtw,
                                                 const float* __restrict__ dtb,
                                                 const float* __restrict__ hin,
                                                 float* __restrict__ ys) {
  const int cb = blockIdx.x;  // 48
  const int db = blockIdx.y;  // 3
  const int bk = blockIdx.z;  // 8
  const int b = bk >> 2, k = bk & 3;
  const int l0 = cb * 48;
  __shared__ __align__(16) float2 sdx[48 * 64];
  __shared__ __align__(16) float  sb[48 * NCH];
  __shared__ __align__(16) float  sc[48 * NCH];
  const int tid = threadIdx.x;
  const int dd = tid & 63, cg = tid >> 6;
  const int dg = db * 64 + dd;
  float b6 = dtb[k * ECH + dg];
  float w6[6];
  {
    const float2* d2 = (const float2*)(dtw + (k * ECH + dg) * 6);
    float2 u0 = d2[0], u1 = d2[1], u2 = d2[2];
    w6[0] = u0.x; w6[1] = u0.y; w6[2] = u1.x; w6[3] = u1.y; w6[4] = u2.x; w6[5] = u2.y;
  }
  for (int idx = tid; idx < 48 * NCH; idx += 256) {
    sb[idx] = bT[(bk * LTOT + l0) * NCH + idx];
    sc[idx] = cT[(bk * LTOT + l0) * NCH + idx];
  }
  for (int e = tid; e < 48 * 64; e += 256) {
    int s = e >> 6;
    const float* d6 = dl6g + (bk * LTOT + l0 + s) * 6;
    float xa = b6;
#pragma unroll
    for (int r = 0; r < 6; ++r) xa = fmaf(w6[r], d6[r], xa);
    float dl = sp_fast(xa);
    int sp = permS(k, l0 + s);
    sdx[s * 64 + dd] = make_float2(dl, dl * xi[(b * LTOT + sp) * ECH + dg]);
  }
  float C1[16], h[16];
  const int c = cb * 4 + cg;
  const float4* hp = (const float4*)(hin + ((bk * CCH + c) * ECH + dg) * NCH);
  {
    float4 h0 = hp[0], h1 = hp[1], h2 = hp[2], h3 = hp[3];
    h[0]=h0.x; h[1]=h0.y; h[2]=h0.z; h[3]=h0.w;
    h[4]=h1.x; h[5]=h1.y; h[6]=h1.z; h[7]=h1.w;
    h[8]=h2.x; h[9]=h2.y; h[10]=h2.z; h[11]=h2.w;
    h[12]=h3.x; h[13]=h3.y; h[14]=h3.z; h[15]=h3.w;
  }
#pragma unroll
  for (int n = 0; n < 16; ++n) C1[n] = Alog[(k * ECH + dg) * NCH + n];
  __syncthreads();
  for (int i = 0; i < SCH; ++i) {
    int j = cg * SCH + i;
    float2 dx = sdx[j * 64 + dd];
    float dl = dx.x;
    float u  = dx.y;
    const float4* bb4 = (const float4*)(sb + j * NCH);
    float4 q0 = bb4[0], q1 = bb4[1], q2 = bb4[2], q3 = bb4[3];
    float bbl[16] = {q0.x, q0.y, q0.z, q0.w, q1.x, q1.y, q1.z, q1.w,
                     q2.x, q2.y, q2.z, q2.w, q3.x, q3.y, q3.z, q3.w};
    if (dl <= 0.018f) {
#pragma unroll
      for (int n = 0; n < 16; ++n) {
        float xn = C1[n] * dl;
        float e = fmaf(xn, fmaf(xn, fmaf(xn, -(1.f / 6.f), 0.5f), -1.f), 1.f);
        h[n] = fmaf(e, h[n], u * bbl[n]);
      }
    } else {
#pragma unroll
      for (int n = 0; n < 16; ++n) {
        float e = __expf(-C1[n] * dl);
        h[n] = fmaf(e, h[n], u * bbl[n]);
      }
    }
    const float4* cc4 = (const float4*)(sc + j * NCH);
    float4 c0 = cc4[0], c1 = cc4[1], c2 = cc4[2], c3 = cc4[3];
    float ccl[16] = {c0.x, c0.y, c0.z, c0.w, c1.x, c1.y, c1.z, c1.w,
                     c2.x, c2.y, c2.z, c2.w, c3.x, c3.y, c3.z, c3.w};
    float y = 0.f;
#pragma unroll
    for (int n = 0; n < 16; ++n) y = fmaf(h[n], ccl[n], y);
    int sp = permS(k, l0 + j);
    atomicAdd(&ys[(b * LTOT + sp) * ECH + dg], y);
  }
}

// ---------------- K5: LayerNorm over E (+Ds) on ys, * z ----------------
__global__ __launch_bounds__(256) void k5_ln(const float* __restrict__ ys,
                                             const float* __restrict__ Ds,
                                             const float* __restrict__ lng,
                                             const float* __restrict__ lnb,
                                             float* __restrict__ zu) {
  int p = blockIdx.x * 4 + (threadIdx.x >> 6);
  int lane = threadIdx.x & 63;
  const float* yp = ys + p * ECH;
  float vd[3], sd[3];
#pragma unroll
  for (int t = 0; t < 3; ++t) {
    int d = lane + t * 64;
    vd[t] = yp[d];
    sd[t] = Ds[d] + Ds[ECH + d] + Ds[2 * ECH + d] + Ds[3 * ECH + d];
  }
  float s1 = vd[0] + vd[1] + vd[2];
  float s2 = sd[0] + sd[1] + sd[2];
#pragma unroll
  for (int off = 32; off > 0; off >>= 1) {
    s1 += __shfl_xor(s1, off, 64);
    s2 += __shfl_xor(s2, off, 64);
  }
  float mean_dot = s1 * (1.f / 192.f);
  float mean_sd  = s2 * (1.f / 192.f);
  float dev[3];
  float ss = 0.f;
#pragma unroll
  for (int t = 0; t < 3; ++t) {
    dev[t] = (vd[t] - mean_dot) + (sd[t] - mean_sd);
    ss = fmaf(dev[t], dev[t], ss);
  }
#pragma unroll
  for (int off = 32; off > 0; off >>= 1) ss += __shfl_xor(ss, off, 64);
  float rstd = 1.f / sqrtf(ss * (1.f / 192.f) + 1e-5f);
#pragma unroll
  for (int t = 0; t < 3; ++t) {
    int d = lane + t * 64;
    float yn = (dev[t] * rstd) * lng[d] + lnb[d];
    zu[p * ECH + d] = yn * zu[p * ECH + d];
  }
}

// ---------------- K6: c1 1x1 GEMM (384x192) + bn1 + relu -> t1 (B,384,L); zeroes se ----------------
__global__ __launch_bounds__(256) void k6_c1(const float* __restrict__ u,
                                             const float* __restrict__ W,
                                             const float* __restrict__ c1b,
                                             const float* __restrict__ g1,
                                             const float* __restrict__ b1,
                                             const float* __restrict__ m1,
                                             const float* __restrict__ v1,
                                             float* __restrict__ t1,
                                             float* __restrict__ se) {
  const int l0 = blockIdx.x * 32;  // 72
  const int o0 = blockIdx.y * 64;  // 6
  const int b  = blockIdx.z;
  const int tid = threadIdx.x;
  if (blockIdx.x == 0 && blockIdx.y == 0 && blockIdx.z == 0 && tid < 192) se[tid] = 0.f;
  __shared__ __align__(16) float xs[96 * 34];  // [c][pos]
  __shared__ __align__(16) float Wl[96 * 68];  // [c][r]
  const int lane = tid & 63, w = tid >> 6;
  const int jj = lane & 15, rqq = lane >> 4;
  const int rbase = 16 * w + 4 * rqq;
  float acc[2][4];
#pragma unroll
  for (int p = 0; p < 2; ++p)
#pragma unroll
    for (int t = 0; t < 4; ++t) acc[p][t] = 0.f;
  for (int kc = 0; kc < 2; ++kc) {
    if (kc) __syncthreads();
    for (int idx = tid; idx < 32 * 96; idx += 256) {
      int cc = idx % 96, i = idx / 96;
      xs[cc * 34 + i] = u[(b * LTOT + l0 + i) * ECH + kc * 96 + cc];
    }
    for (int idx = tid; idx < 96 * 16; idx += 256) {
      int cc = idx % 96, rq = idx / 96;
      float4 v;
      v.x = W[(o0 + 4 * rq + 0) * ECH + kc * 96 + cc];
      v.y = W[(o0 + 4 * rq + 1) * ECH + kc * 96 + cc];
      v.z = W[(o0 + 4 * rq + 2) * ECH + kc * 96 + cc];
      v.w = W[(o0 + 4 * rq + 3) * ECH + kc * 96 + cc];
      *(float4*)&Wl[cc * 68 + 4 * rq] = v;
    }
    __syncthreads();
#pragma unroll 4
    for (int cc = 0; cc < 96; ++cc) {
      const float4 wv = *(const float4*)&Wl[cc * 68 + rbase];
      const float2 xv = *(const float2*)&xs[cc * 34 + 2 * jj];
      acc[0][0] = fmaf(wv.x, xv.x, acc[0][0]); acc[0][1] = fmaf(wv.y, xv.x, acc[0][1]);
      acc[0][2] = fmaf(wv.z, xv.x, acc[0][2]); acc[0][3] = fmaf(wv.w, xv.x, acc[0][3]);
      acc[1][0] = fmaf(wv.x, xv.y, acc[1][0]); acc[1][1] = fmaf(wv.y, xv.y, acc[1][1]);
      acc[1][2] = fmaf(wv.z, xv.y, acc[1][2]); acc[1][3] = fmaf(wv.w, xv.y, acc[1][3]);
    }
  }
#pragma unroll
  for (int t = 0; t < 4; ++t) {
    int o = o0 + rbase + t;
    float sc = g1[o] / sqrtf(v1[o] + 1e-5f);
    float bias = (c1b[o] - m1[o]) * sc + b1[o];
#pragma unroll
    for (int p = 0; p < 2; ++p) acc[p][t] = fmaxf(fmaf(acc[p][t], sc, bias), 0.f);
  }
  __syncthreads();
  float* ol = xs;  // [r][pos] pad 33
#pragma unroll
  for (int t = 0; t < 4; ++t) {
    ol[(rbase + t) * 33 + 2 * jj]     = acc[0][t];
    ol[(rbase + t) * 33 + 2 * jj + 1] = acc[1][t];
  }
  __syncthreads();
  for (int idx = tid; idx < 32 * 64; idx += 256) {
    int pos = idx & 31, r = idx >> 5;
    t1[(b * 384 + o0 + r) * LTOT + l0 + pos] = ol[r * 33 + pos];
  }
}

// ---------------- K7: depthwise 3x3 on t1 (B,384,L) + bn2 + relu. float4 over l. ----------------
__global__ __launch_bounds__(256) void k7_dw2(const float* __restrict__ t1,
                                              const float* __restrict__ cw,
                                              const float* __restrict__ cb,
                                              const float* __restrict__ g2,
                                              const float* __restrict__ b2,
                                              const float* __restrict__ m2,
                                              const float* __restrict__ v2,
                                              float* __restrict__ t2) {
  int g = blockIdx.x * 256 + threadIdx.x;
  if (g >= 2 * 384 * 576) return;
  int p = g % 576; int o = (g / 576) % 384; int b = g / (576 * 384);
  int l0 = 4 * p; int h = l0 / 48; int wq0 = l0 % 48;
  const float* src = t1 + (b * 384 + o) * LTOT;
  float wt[9];
#pragma unroll
  for (int t = 0; t < 9; ++t) wt[t] = cw[o * 9 + t];
  float bias0 = cb[o];
  float4 a = make_float4(bias0, bias0, bias0, bias0);
#pragma unroll
  for (int kh = 0; kh < 3; ++kh) {
    int hh = h + kh - 1; if (hh < 0 || hh >= 48) continue;
    const float* row = src + hh * 48;
    float4 c = *(const float4*)(row + wq0);
    float lft = (wq0 > 0)  ? row[wq0 - 1] : 0.f;
    float rgt = (wq0 < 44) ? row[wq0 + 4] : 0.f;
    float w0 = wt[kh * 3], w1 = wt[kh * 3 + 1], w2 = wt[kh * 3 + 2];
    a.x = fmaf(w0, lft, fmaf(w1, c.x, fmaf(w2, c.y, a.x)));
    a.y = fmaf(w0, c.x, fmaf(w1, c.y, fmaf(w2, c.z, a.y)));
    a.z = fmaf(w0, c.y, fmaf(w1, c.z, fmaf(w2, c.w, a.z)));
    a.w = fmaf(w0, c.z, fmaf(w1, c.w, fmaf(w2, rgt, a.w)));
  }
  float sc = g2[o] / sqrtf(v2[o] + 1e-5f);
  float bs = (0.f - m2[o]) * sc + b2[o];
  a.x = fmaxf(fmaf(a.x, sc, bs), 0.f);
  a.y = fmaxf(fmaf(a.y, sc, bs), 0.f);
  a.z = fmaxf(fmaf(a.z, sc, bs), 0.f);
  a.w = fmaxf(fmaf(a.w, sc, bs), 0.f);
  *(float4*)(t2 + (b * 384 + o) * LTOT + l0) = a;
}

// ---------------- K8: c3 1x1 GEMM (96x384) on t2 (B,384,L) -> t3 (B,96,L) + SE sums ----------------
__global__ __launch_bounds__(256) void k8_c3(const float* __restrict__ t2,
                                             const float* __restrict__ W,
                                             const float* __restrict__ c3b,
                                             float* __restrict__ t3,
                                             float* __restrict__ se) {
  const int l0 = blockIdx.x * 32;  // 72
  const int r0 = blockIdx.y * 32;  // 3
  const int b  = blockIdx.z;       // 2
  __shared__ __align__(16) float Wl[384 * 34];  // [c][r]
  __shared__ __align__(16) float xs[192 * 34];  // [c][i] per K-half
  const int tid = threadIdx.x;
  const int lane = tid & 63, w = tid >> 6;
  const int jj = lane & 15, rqq = lane >> 4;
  const int rloc = 8 * w + 2 * rqq;
  for (int idx = tid; idx < 32 * 384; idx += 256) {
    int r = idx / 384, cc = idx - r * 384;
    Wl[cc * 34 + r] = W[(r0 + r) * 384 + cc];
  }
  float acc[2][2];
  acc[0][0] = acc[0][1] = acc[1][0] = acc[1][1] = 0.f;
  for (int kc = 0; kc < 2; ++kc) {
    if (kc) __syncthreads();
    for (int idx = tid; idx < 192 * 32; idx += 256) {
      int i = idx & 31, cc = idx >> 5;
      xs[cc * 34 + i] = t2[(b * 384 + kc * 192 + cc) * LTOT + l0 + i];
    }
    __syncthreads();
#pragma unroll 4
    for (int cc = 0; cc < 192; ++cc) {
      const float2 wv = *(const float2*)&Wl[(kc * 192 + cc) * 34 + rloc];
      const float2 xv = *(const float2*)&xs[cc * 34 + 2 * jj];
      acc[0][0] = fmaf(wv.x, xv.x, acc[0][0]); acc[0][1] = fmaf(wv.y, xv.x, acc[0][1]);
      acc[1][0] = fmaf(wv.x, xv.y, acc[1][0]); acc[1][1] = fmaf(wv.y, xv.y, acc[1][1]);
    }
  }
  {
    float b0 = c3b[r0 + rloc], b1v = c3b[r0 + rloc + 1];
    acc[0][0] += b0; acc[1][0] += b0; acc[0][1] += b1v; acc[1][1] += b1v;
  }
#pragma unroll
  for (int t = 0; t < 2; ++t) {
    float v = acc[0][t] + acc[1][t];
    v += __shfl_xor(v, 1); v += __shfl_xor(v, 2);
    v += __shfl_xor(v, 4); v += __shfl_xor(v, 8);
    if (jj == 0) atomicAdd(&se[b * 96 + r0 + rloc + t], v);
  }
  __syncthreads();
  float* ol = xs;  // [r][pos] pad 33
#pragma unroll
  for (int t = 0; t < 2; ++t) {
    ol[(rloc + t) * 33 + 2 * jj]     = acc[0][t];
    ol[(rloc + t) * 33 + 2 * jj + 1] = acc[1][t];
  }
  __syncthreads();
  for (int idx = tid; idx < 32 * 32; idx += 256) {
    int pos = idx & 31, r = idx >> 5;
    t3[(b * 96 + r0 + r) * LTOT + l0 + pos] = ol[r * 33 + pos];
  }
}

// ---------------- K9: SE MLP (per-block, redundant) + out = t3 * (1+sigmoid) ----------------
__global__ __launch_bounds__(256) void k9_out(const float* __restrict__ t3,
                                              const float* __restrict__ se,
                                              const float* __restrict__ w1,
                                              const float* __restrict__ sb1,
                                              const float* __restrict__ w2,
                                              const float* __restrict__ sb2,
                                              float* __restrict__ out) {
  __shared__ float sm[192];
  __shared__ float s1[96];
  __shared__ float smul[192];
  int t = threadIdx.x;
  if (t < 192) sm[t] = se[t] * (1.f / 2304.f);
  __syncthreads();
  if (t < 96) {
    int b = t / 48, i = t % 48;
    float a = sb1[i];
#pragma unroll 4
    for (int m = 0; m < 96; ++m) a = fmaf(w1[i * 96 + m], sm[b * 96 + m], a);
    s1[t] = fmaxf(a, 0.f);
  }
  __syncthreads();
  if (t < 192) {
    int b = t / 96, j = t % 96;
    float a = sb2[j];
#pragma unroll 4
    for (int i = 0; i < 48; ++i) a = fmaf(w2[j * 48 + i], s1[b * 48 + i], a);
    smul[t] = 1.f + 1.f / (1.f + __expf(-a));
  }
  __syncthreads();
  int g = blockIdx.x * 256 + t;
  if (g < 2 * 96 * LTOT) out[g] = t3[g] * smul[g / LTOT];
}

extern "C" void kernel_launch(void* const* d_in, const int* in_sizes, int n_in,
                              void* d_out, int out_size, void* d_ws, size_t ws_size,
                              hipStream_t stream) {
  const float* x     = (const float*)d_in[0];
  const float* inw   = (const float*)d_in[1];
  const float* convw = (const float*)d_in[2];
  const float* convb = (const float*)d_in[3];
  const float* xpw   = (const float*)d_in[4];
  const float* dtw   = (const float*)d_in[5];
  const float* dtb   = (const float*)d_in[6];
  const float* Alog  = (const float*)d_in[7];
  const float* Ds    = (const float*)d_in[8];
  const float* lng   = (const float*)d_in[9];
  const float* lnb   = (const float*)d_in[10];
  const float* c1w   = (const float*)d_in[11];
  const float* c1b   = (const float*)d_in[12];
  const float* bn1g  = (const float*)d_in[13];
  const float* bn1b  = (const float*)d_in[14];
  const float* bn1m  = (const float*)d_in[15];
  const float* bn1v  = (const float*)d_in[16];
  const float* c2w   = (const float*)d_in[17];
  const float* c2b   = (const float*)d_in[18];
  const float* bn2g  = (const float*)d_in[19];
  const float* bn2b  = (const float*)d_in[20];
  const float* bn2m  = (const float*)d_in[21];
  const float* bn2v  = (const float*)d_in[22];
  const float* c3w   = (const float*)d_in[23];
  const float* c3b   = (const float*)d_in[24];
  const float* se1w  = (const float*)d_in[25];
  const float* se1b  = (const float*)d_in[26];
  const float* se2w  = (const float*)d_in[27];
  const float* se2b  = (const float*)d_in[28];

  float* ws = (float*)d_ws;
  float* xi_pre = ws;                    // 884736
  float* z      = ws + 884736;           // 884736 (becomes u after k5)
  float* xi     = ws + 1769472;          // 884736
  float* dl6g   = ws + 2654208;          // 110592
  float* bT     = ws + 2764800;          // 589824
  float* cT     = ws + 3354624;          // 589824
  float* q      = ws + 3944448;          // 9437184 (CCH=192); t1/t2/t3 reuse (dead after k4c)
  float* Ts     = ws + 13381632;         // 294912
  float* se     = ws + 13676544;         // 192
  float* ys     = ws + 13676736;         // 884736
  float* t1 = q;
  float* t2 = q + 1769472;
  float* t3 = q + 3538944;

  hipMemsetAsync(ys, 0, 884736 * sizeof(float), stream);

  k1_inproj<<<dim3(72, 6, 2), 256, 0, stream>>>(x, inw, xi_pre, z);
  k2_dwconv<<<864, 256, 0, stream>>>((const float4*)xi_pre, convw, convb, (float4*)xi);
  k3_xproj<<<dim3(72, 4, 2), 256, 0, stream>>>(xi, xpw, dl6g, bT, cT);
  k4a_scan1<<<dim3(48, 3, 8), 256, 0, stream>>>(dl6g, xi, bT, Alog, dtw, dtb, q, Ts);
  k4b_comb<<<dim3(192, 8), 256, 0, stream>>>(Alog, Ts, q);
  k4c_scan2<<<dim3(48, 3, 8), 256, 0, stream>>>(dl6g, xi, bT, cT, Alog, dtw, dtb, q, ys);
  k5_ln<<<1152, 256, 0, stream>>>(ys, Ds, lng, lnb, z);
  k6_c1<<<dim3(72, 6, 2), 256, 0, stream>>>(z, c1w, c1b, bn1g, bn1b, bn1m, bn1v, t1, se);
  k7_dw2<<<1728, 256, 0, stream>>>(t1, c2w, c2b, bn2g, bn2b, bn2m, bn2v, t2);
  k8_c3<<<dim3(72, 3, 2), 256, 0, stream>>>(t2, c3w, c3b, t3, se);
  k9_out<<<1728, 256, 0, stream>>>(t3, se, se1w, se1b, se2w, se2b, (float*)d_out);
}